// Round 3
// baseline (7617.289 us; speedup 1.0000x reference)
//
#include <hip/hip_runtime.h>
#include <hip/hip_bf16.h>
#include <math.h>

// Problem constants
#define BB 4
#define SEQL 12
#define NN 1024
#define SEGL 3
#define SEGN 4
#define HID 64
#define FFD 2048
#define DKK 32
#define NHH 8
#define HDD 8

using bf16 = __hip_bfloat16;
__device__ __forceinline__ float b2f(bf16 v) { return __bfloat162float(v); }

// dtype-templated weight load: F=1 fp32 storage, F=0 bf16 storage
template <int F>
__device__ __forceinline__ float ldw(const void* p, long i) {
  if (F) return ((const float*)p)[i];
  return b2f(((const bf16*)p)[i]);
}

// ---------------------------------------------------------------- zero-fill d_out (guard path + never-empty-graph)
__global__ void k_zero(unsigned short* __restrict__ o, int n) {
  int i = blockIdx.x * 256 + threadIdx.x;
  if (i < n) o[i] = 0;
}

// ---------------------------------------------------------------- detect dtype
// fp32 storage read as bf16 -> every other 16-bit half is fp32 mantissa bits
// (≈ uniform-exponent garbage). bf16 storage -> values look like N(0,1).
__global__ void k_detect(const void* __restrict__ x0, int* __restrict__ flag) {
  int t = threadIdx.x;
  int bad = 0;
  const bf16* p = (const bf16*)x0;
  for (int i = t; i < 512; i += 256) {
    float a = fabsf(b2f(p[i]));
    if (!(a < 1e4f) || (a != 0.f && a < 1e-4f)) bad = 1;
  }
  __shared__ int tot;
  if (t == 0) tot = 0;
  __syncthreads();
  unsigned long long m = __ballot(bad);
  if ((t & 63) == 0) atomicAdd(&tot, __popcll(m));
  __syncthreads();
  if (t == 0) *flag = (tot > 64) ? 1 : 0;   // 1 = fp32 storage, 0 = bf16
}

// ---------------------------------------------------------------- patch embed
// z[b,n,g,h] = sum_l x[b, g*3+l, n]*pw[h,l] + pb[h] + pe[g,h]
template <int F>
__global__ __launch_bounds__(256) void k_patch(const void* __restrict__ x,
    const void* __restrict__ pw, long opw, const void* __restrict__ pb, long opb,
    float* __restrict__ z, const int* __restrict__ flag) {
  if (*flag != F) return;
  int b = blockIdx.x >> 10, n = blockIdx.x & 1023;
  int g = threadIdx.x >> 6, h = threadIdx.x & 63;
  float acc = ldw<F>(pb, opb + h);
#pragma unroll
  for (int l = 0; l < SEGL; ++l)
    acc += ldw<F>(x, (long)(b*SEQL + g*SEGL + l)*NN + n) * ldw<F>(pw, opw + h*SEGL + l);
  int i2 = h >> 1;
  float dv = expf((float)(2*i2) * (-logf(10000.f) / (float)HID));
  float ang = (float)g * dv;
  acc += (h & 1) ? cosf(ang) : sinf(ang);
  z[((long)(b*NN + n)*SEGN + g)*HID + h] = acc;
}

// ---------------------------------------------------------------- temporal MHA + LN1
// One 64-thread block per (b,n): 4 tokens x 64 dims, post-norm.
template <int F>
__global__ __launch_bounds__(64) void k_tattn(float* __restrict__ z,
    const void* __restrict__ W, long oW, const void* __restrict__ bqkv, long obq,
    const void* __restrict__ WO, long oWO, const void* __restrict__ bo, long obo,
    const void* __restrict__ g1, long og1, const void* __restrict__ b1, long ob1,
    const int* __restrict__ flag) {
  if (*flag != F) return;
  __shared__ float xr[SEGN][HID];
  __shared__ float qkv[SEGN][3*HID];
  __shared__ float ao[SEGN][HID];
  __shared__ float mst[SEGN][2];
  int h = threadIdx.x;
  float* zp = z + (long)blockIdx.x * SEGN * HID;
#pragma unroll
  for (int g = 0; g < SEGN; ++g) xr[g][h] = zp[g*HID + h];
  __syncthreads();
#pragma unroll
  for (int j = 0; j < 3; ++j) {
    int c = j*HID + h;
    long wr = oW + (long)c*HID;
    float a0=0,a1=0,a2=0,a3=0;
    for (int k = 0; k < HID; ++k) {
      float w = ldw<F>(W, wr + k);
      a0 += xr[0][k]*w; a1 += xr[1][k]*w; a2 += xr[2][k]*w; a3 += xr[3][k]*w;
    }
    float bb = ldw<F>(bqkv, obq + c);
    qkv[0][c]=a0+bb; qkv[1][c]=a1+bb; qkv[2][c]=a2+bb; qkv[3][c]=a3+bb;
  }
  __syncthreads();
  if (h < NHH*SEGN) {
    int head = h >> 2, qt = h & 3;
    const float scale = 0.3535533905932738f;   // 1/sqrt(8)
    float s[SEGN]; float mx = -1e30f;
#pragma unroll
    for (int kt = 0; kt < SEGN; ++kt) {
      float d = 0;
#pragma unroll
      for (int e = 0; e < HDD; ++e) d += qkv[qt][head*HDD+e]*qkv[kt][HID+head*HDD+e];
      s[kt] = d*scale; mx = fmaxf(mx, s[kt]);
    }
    float se = 0;
#pragma unroll
    for (int kt = 0; kt < SEGN; ++kt) { s[kt] = expf(s[kt]-mx); se += s[kt]; }
    float inv = 1.f/se;
#pragma unroll
    for (int e = 0; e < HDD; ++e) {
      float o = 0;
#pragma unroll
      for (int kt = 0; kt < SEGN; ++kt) o += s[kt]*qkv[kt][2*HID+head*HDD+e];
      ao[qt][head*HDD+e] = o*inv;
    }
  }
  __syncthreads();
  float y[SEGN];
  {
    long wr = oWO + (long)h*HID;
    float bb = ldw<F>(bo, obo + h);
#pragma unroll
    for (int g = 0; g < SEGN; ++g) {
      float a = bb;
      for (int k = 0; k < HID; ++k) a += ao[g][k]*ldw<F>(WO, wr + k);
      y[g] = xr[g][h] + a;    // residual
    }
  }
  __syncthreads();
#pragma unroll
  for (int g = 0; g < SEGN; ++g) xr[g][h] = y[g];
  __syncthreads();
  if (h < SEGN) {
    float m = 0;
    for (int k = 0; k < HID; ++k) m += xr[h][k];
    m *= (1.f/HID);
    float v = 0;
    for (int k = 0; k < HID; ++k) { float d = xr[h][k]-m; v += d*d; }
    mst[h][0] = m; mst[h][1] = rsqrtf(v*(1.f/HID) + 1e-5f);
  }
  __syncthreads();
  float gg = ldw<F>(g1, og1 + h), bb2 = ldw<F>(b1, ob1 + h);
#pragma unroll
  for (int g = 0; g < SEGN; ++g)
    zp[g*HID + h] = (y[g]-mst[g][0])*mst[g][1]*gg + bb2;
}

// ---------------------------------------------------------------- FF + residual + LN
// out = LN(x + relu(x@W1^T+B1)@W2^T+B2). 8 rows/block, one wave per row.
// Streaming 128-wide hidden tiles; LDS = 2 + 4 + 33.3 = 39.4 KB (< 64 KB).
#define FFROWS 8
template <int F>
__global__ __launch_bounds__(512) void k_ffln(float* __restrict__ x,
    const void* __restrict__ W1, long o1, const void* __restrict__ B1, long ob1,
    const void* __restrict__ W2, long o2, const void* __restrict__ B2, long ob2,
    const void* __restrict__ G, long og, const void* __restrict__ Bt, long obt,
    const int* __restrict__ flag) {
  if (*flag != F) return;
  __shared__ float xs[FFROWS][HID];
  __shared__ float ht[FFROWS][128];
  __shared__ float tile[8320];           // max(128*65, 64*130)
  int tid = threadIdx.x;
  int wave = tid >> 6, lane = tid & 63;
  long base = (long)blockIdx.x * FFROWS * HID;
  xs[wave][lane] = x[base + tid];
  float acc = ldw<F>(B2, ob2 + lane);
  for (int j0 = 0; j0 < FFD; j0 += 128) {
    __syncthreads();                     // protect tile/ht reuse
    for (int i = tid; i < 128*64; i += 512)
      tile[(i >> 6)*65 + (i & 63)] = ldw<F>(W1, o1 + (long)j0*HID + i);
    __syncthreads();
#pragma unroll
    for (int half = 0; half < 2; ++half) {
      int jj = half*64 + lane;
      float a = ldw<F>(B1, ob1 + j0 + jj);
      const float* wt = &tile[jj*65];
      for (int e = 0; e < HID; ++e) a += xs[wave][e]*wt[e];
      ht[wave][jj] = fmaxf(a, 0.f);
    }
    __syncthreads();
    for (int i = tid; i < 64*128; i += 512)
      tile[(i >> 7)*130 + (i & 127)] = ldw<F>(W2, o2 + (long)(i >> 7)*FFD + j0 + (i & 127));
    __syncthreads();
    const float* wt = &tile[lane*130];
    const float* hp = ht[wave];
    for (int jj = 0; jj < 128; ++jj) acc += hp[jj]*wt[jj];
  }
  float val = xs[wave][lane] + acc;
  float s = val;
#pragma unroll
  for (int off = 32; off; off >>= 1) s += __shfl_xor(s, off);
  float m = s * (1.f/HID);
  float d = val - m;
  float sq = d*d;
#pragma unroll
  for (int off = 32; off; off >>= 1) sq += __shfl_xor(sq, off);
  float r = rsqrtf(sq*(1.f/HID) + 1e-5f);
  x[base + wave*HID + lane] = d*r*ldw<F>(G, og + lane) + ldw<F>(Bt, obt + lane);
}

// ---------------------------------------------------------------- graph qkv proj
template <int F>
__global__ __launch_bounds__(128) void k_gqkv(const float* __restrict__ z,
    const void* __restrict__ wq, long oq, const void* __restrict__ wk, long ok,
    const void* __restrict__ wv, long ov,
    float* __restrict__ q, float* __restrict__ k, float* __restrict__ v,
    const int* __restrict__ flag) {
  if (*flag != F) return;
  __shared__ float xs[HID];
  int bg = blockIdx.x >> 10, n = blockIdx.x & 1023;
  int b = bg >> 2, g = bg & 3;
  const float* zp = z + ((long)(b*NN + n)*SEGN + g)*HID;
  int t = threadIdx.x;
  if (t < HID) xs[t] = zp[t];
  __syncthreads();
  long r = (long)bg*NN + n;
  if (t < 32) {
    long wr = oq + (long)t*HID; float a = 0;
    for (int e = 0; e < HID; ++e) a += xs[e]*ldw<F>(wq, wr + e);
    q[r*DKK + t] = a;
  } else if (t < 64) {
    long wr = ok + (long)(t-32)*HID; float a = 0;
    for (int e = 0; e < HID; ++e) a += xs[e]*ldw<F>(wk, wr + e);
    k[r*DKK + (t-32)] = a;
  } else {
    long wr = ov + (long)(t-64)*HID; float a = 0;
    for (int e = 0; e < HID; ++e) a += xs[e]*ldw<F>(wv, wr + e);
    v[r*HID + (t-64)] = a;
  }
}

// ---------------------------------------------------------------- graph attention
// 8 queries per 256-thread block; full 1024 score row in LDS; LN(att)+x in-place.
// LDS: 1 + 32 + 16.9 + 2 = 52.7 KB.
#define QB 8
#define TM 64
__global__ __launch_bounds__(256) void k_gattn(float* __restrict__ z,
    const float* __restrict__ q, const float* __restrict__ k,
    const float* __restrict__ v,
    const void* __restrict__ g1, long og1, const void* __restrict__ b1, long ob1,
    const int* __restrict__ flag) {
  int f = *flag;
  __shared__ float qs[QB][DKK];
  __shared__ float sc[QB][NN];
  __shared__ float tile[TM*66];
  __shared__ float oacc[QB][HID];
  int tid = threadIdx.x;
  int wave = tid >> 6, lane = tid & 63;
  int bg = blockIdx.x >> 7;
  int n0 = (blockIdx.x & 127) * QB;
  if (tid < QB*DKK)
    qs[tid >> 5][tid & 31] = q[((long)bg*NN + n0 + (tid >> 5))*DKK + (tid & 31)];
  __syncthreads();
  const float rs = 0.17677669529663687f;   // 1/sqrt(32)
  for (int m0 = 0; m0 < NN; m0 += TM) {
    for (int i = tid; i < TM*DKK; i += 256)
      tile[(i >> 5)*33 + (i & 31)] = k[((long)bg*NN + m0)*DKK + i];
    __syncthreads();
    for (int tt = tid; tt < QB*TM; tt += 256) {
      int qq = tt >> 6, mm = tt & 63;
      const float* kt = &tile[mm*33];
      const float* qp = qs[qq];
      float a = 0;
#pragma unroll
      for (int e = 0; e < DKK; ++e) a += qp[e]*kt[e];
      sc[qq][m0 + mm] = a*rs;
    }
    __syncthreads();
  }
  for (int qq = wave*2; qq < wave*2 + 2; ++qq) {
    float mx = -1e30f;
    for (int mm = lane; mm < NN; mm += 64) mx = fmaxf(mx, sc[qq][mm]);
#pragma unroll
    for (int off = 32; off; off >>= 1) mx = fmaxf(mx, __shfl_xor(mx, off));
    float se = 0;
    for (int mm = lane; mm < NN; mm += 64) { float e = expf(sc[qq][mm]-mx); sc[qq][mm] = e; se += e; }
#pragma unroll
    for (int off = 32; off; off >>= 1) se += __shfl_xor(se, off);
    float inv = 1.f/se;
    for (int mm = lane; mm < NN; mm += 64) sc[qq][mm] *= inv;
  }
  for (int i = tid; i < QB*HID; i += 256) oacc[i >> 6][i & 63] = 0.f;
  __syncthreads();
  for (int m0 = 0; m0 < NN; m0 += TM) {
    for (int i = tid; i < TM*HID; i += 256)
      tile[i] = v[((long)bg*NN + m0)*HID + i];
    __syncthreads();
    for (int tt = tid; tt < QB*HID; tt += 256) {
      int qq = tt >> 6, hh = tt & 63;
      float a = oacc[qq][hh];
      const float* sp = &sc[qq][m0];
      for (int mm = 0; mm < TM; ++mm) a += sp[mm]*tile[mm*HID + hh];
      oacc[qq][hh] = a;
    }
    __syncthreads();
  }
  int b = bg >> 2, g = bg & 3;
  float gg = f ? ((const float*)g1)[og1 + lane] : b2f(((const bf16*)g1)[og1 + lane]);
  float bb = f ? ((const float*)b1)[ob1 + lane] : b2f(((const bf16*)b1)[ob1 + lane]);
  for (int qq = wave*2; qq < wave*2 + 2; ++qq) {
    float val = oacc[qq][lane];
    float s = val;
#pragma unroll
    for (int off = 32; off; off >>= 1) s += __shfl_xor(s, off);
    float m = s*(1.f/HID);
    float d = val - m, sq = d*d;
#pragma unroll
    for (int off = 32; off; off >>= 1) sq += __shfl_xor(sq, off);
    float r = rsqrtf(sq*(1.f/HID) + 1e-5f);
    float* zp = z + ((long)(b*NN + n0 + qq)*SEGN + g)*HID;
    zp[lane] = d*r*gg + bb + zp[lane];   // LN(att) + x
  }
}

// ---------------------------------------------------------------- pool over segments
__global__ __launch_bounds__(64) void k_pool(const float* __restrict__ z,
    float* __restrict__ enc, int s) {
  int b = blockIdx.x >> 10, n = blockIdx.x & 1023, h = threadIdx.x;
  const float* zp = z + (long)(b*NN + n)*SEGN*HID;
  float a = 0;
#pragma unroll
  for (int g = 0; g < SEGN; ++g) a += zp[g*HID + h];
  enc[(long)(b*NN + n)*(2*HID) + s*HID + h] = a*0.25f;
}

// ---------------------------------------------------------------- final qkv proj (in_dim=128)
template <int F>
__global__ __launch_bounds__(128) void k_fqkv(const float* __restrict__ enc,
    const void* __restrict__ wq, const void* __restrict__ wk,
    const void* __restrict__ wv,
    float* __restrict__ q, float* __restrict__ k, float* __restrict__ v,
    const int* __restrict__ flag) {
  if (*flag != F) return;
  __shared__ float xs[2*HID];
  long r = blockIdx.x;
  int t = threadIdx.x;
  xs[t] = enc[r*128 + t];
  __syncthreads();
  if (t < 32) {
    long wr = (long)t*128; float a = 0;
    for (int e = 0; e < 128; ++e) a += xs[e]*ldw<F>(wq, wr + e);
    q[r*DKK + t] = a;
  } else if (t < 64) {
    long wr = (long)(t-32)*128; float a = 0;
    for (int e = 0; e < 128; ++e) a += xs[e]*ldw<F>(wk, wr + e);
    k[r*DKK + (t-32)] = a;
  } else {
    long wr = (long)(t-64)*128; float a = 0;
    for (int e = 0; e < 128; ++e) a += xs[e]*ldw<F>(wv, wr + e);
    v[r*HID + (t-64)] = a;
  }
}

// ---------------------------------------------------------------- final attention -> d_out
__global__ __launch_bounds__(256) void k_fattn(const float* __restrict__ q,
    const float* __restrict__ k, const float* __restrict__ v,
    void* __restrict__ outp, const int* __restrict__ flag) {
  __shared__ float qs[QB][DKK];
  __shared__ float sc[QB][NN];
  __shared__ float tile[TM*66];
  __shared__ float oacc[QB][HID];
  int tid = threadIdx.x;
  int wave = tid >> 6, lane = tid & 63;
  int b = blockIdx.x >> 7;
  int n0 = (blockIdx.x & 127) * QB;
  if (tid < QB*DKK)
    qs[tid >> 5][tid & 31] = q[((long)b*NN + n0 + (tid >> 5))*DKK + (tid & 31)];
  __syncthreads();
  const float rs = 0.17677669529663687f;
  for (int m0 = 0; m0 < NN; m0 += TM) {
    for (int i = tid; i < TM*DKK; i += 256)
      tile[(i >> 5)*33 + (i & 31)] = k[((long)b*NN + m0)*DKK + i];
    __syncthreads();
    for (int tt = tid; tt < QB*TM; tt += 256) {
      int qq = tt >> 6, mm = tt & 63;
      const float* kt = &tile[mm*33];
      const float* qp = qs[qq];
      float a = 0;
#pragma unroll
      for (int e = 0; e < DKK; ++e) a += qp[e]*kt[e];
      sc[qq][m0 + mm] = a*rs;
    }
    __syncthreads();
  }
  for (int qq = wave*2; qq < wave*2 + 2; ++qq) {
    float mx = -1e30f;
    for (int mm = lane; mm < NN; mm += 64) mx = fmaxf(mx, sc[qq][mm]);
#pragma unroll
    for (int off = 32; off; off >>= 1) mx = fmaxf(mx, __shfl_xor(mx, off));
    float se = 0;
    for (int mm = lane; mm < NN; mm += 64) { float e = expf(sc[qq][mm]-mx); sc[qq][mm] = e; se += e; }
#pragma unroll
    for (int off = 32; off; off >>= 1) se += __shfl_xor(se, off);
    float inv = 1.f/se;
    for (int mm = lane; mm < NN; mm += 64) sc[qq][mm] *= inv;
  }
  for (int i = tid; i < QB*HID; i += 256) oacc[i >> 6][i & 63] = 0.f;
  __syncthreads();
  for (int m0 = 0; m0 < NN; m0 += TM) {
    for (int i = tid; i < TM*HID; i += 256)
      tile[i] = v[((long)b*NN + m0)*HID + i];
    __syncthreads();
    for (int tt = tid; tt < QB*HID; tt += 256) {
      int qq = tt >> 6, hh = tt & 63;
      float a = oacc[qq][hh];
      const float* sp = &sc[qq][m0];
      for (int mm = 0; mm < TM; ++mm) a += sp[mm]*tile[mm*HID + hh];
      oacc[qq][hh] = a;
    }
    __syncthreads();
  }
  int f = *flag;
  for (int qq = wave*2; qq < wave*2 + 2; ++qq) {
    float val = oacc[qq][lane];
    long idx = ((long)(b*NN + n0 + qq))*HID + lane;
    if (f) ((float*)outp)[idx] = val;
    else   ((bf16*)outp)[idx] = __float2bfloat16(val);
  }
}

// ================================================================ launch
extern "C" void kernel_launch(void* const* d_in, const int* in_sizes, int n_in,
                              void* d_out, int out_size, void* d_ws, size_t ws_size,
                              hipStream_t stream) {
  // Expected element counts, setup_inputs() order
  static const int EXP[30] = {
    49152, 49152, 384, 128, 49152, 768, 16384, 256,
    524288, 8192, 524288, 256, 256, 256, 256, 256,
    8192, 8192, 16384, 524288, 8192, 524288, 256, 256,
    256, 256, 256, 4096, 4096, 8192
  };
  // Workspace: z 1,048,576 + enc 524,288 + q 524,288 + k 524,288 + v 1,048,576 fl + flag
  const size_t NEED = (size_t)(1048576 + 524288 + 524288 + 524288 + 1048576) * 4 + 64;
  bool ok = (n_in == 30) && (ws_size >= NEED) && (out_size == BB*NN*HID);
  if (ok) for (int i = 0; i < 30; ++i) ok = ok && (in_sizes[i] == EXP[i]);
  if (!ok) {   // clean diagnostic fail; graph never empty
    k_zero<<<(BB*NN*HID + 255)/256, 256, 0, stream>>>((unsigned short*)d_out, BB*NN*HID);
    return;
  }

  float* z   = (float*)d_ws;             // [4,1024,4,64]
  float* enc = z   + 1048576;            // [4,1024,128]
  float* qb  = enc + 524288;             // [16,1024,32]
  float* kb  = qb  + 524288;             // [16,1024,32]
  float* vb  = kb  + 524288;             // [16,1024,64]
  int*  flag = (int*)(vb + 1048576);

  k_detect<<<1, 256, 0, stream>>>(d_in[0], flag);

  // d_in indices
  const void *i_traffic=d_in[0], *i_user=d_in[1], *i_pw=d_in[2], *i_pb=d_in[3],
    *i_mw=d_in[4], *i_mb=d_in[5], *i_ow=d_in[6], *i_ob=d_in[7], *i_f1w=d_in[8],
    *i_f1b=d_in[9], *i_f2w=d_in[10], *i_f2b=d_in[11], *i_l1g=d_in[12],
    *i_l1b=d_in[13], *i_l2g=d_in[14], *i_l2b=d_in[15], *i_gwq=d_in[16],
    *i_gwk=d_in[17], *i_gwv=d_in[18], *i_gf1w=d_in[19], *i_gf1b=d_in[20],
    *i_gf2w=d_in[21], *i_gf2b=d_in[22], *i_gl1g=d_in[23], *i_gl1b=d_in[24],
    *i_gl2g=d_in[25], *i_gl2b=d_in[26], *i_cwq=d_in[27], *i_cwk=d_in[28],
    *i_cwv=d_in[29];

  for (int s = 0; s < 2; ++s) {
    const void* x = s ? i_user : i_traffic;
    k_patch<0><<<BB*NN, 256, 0, stream>>>(x, i_pw, (long)s*HID*SEGL, i_pb, (long)s*HID, z, flag);
    k_patch<1><<<BB*NN, 256, 0, stream>>>(x, i_pw, (long)s*HID*SEGL, i_pb, (long)s*HID, z, flag);
    for (int i = 0; i < 2; ++i) {
      long si = s*2 + i;
      k_tattn<0><<<BB*NN, 64, 0, stream>>>(z,
          i_mw, si*3*HID*HID, i_mb, si*3*HID, i_ow, si*HID*HID, i_ob, si*HID,
          i_l1g, si*HID, i_l1b, si*HID, flag);
      k_tattn<1><<<BB*NN, 64, 0, stream>>>(z,
          i_mw, si*3*HID*HID, i_mb, si*3*HID, i_ow, si*HID*HID, i_ob, si*HID,
          i_l1g, si*HID, i_l1b, si*HID, flag);
      k_ffln<0><<<BB*NN*SEGN/FFROWS, 512, 0, stream>>>(z,
          i_f1w, si*FFD*HID, i_f1b, si*FFD, i_f2w, si*HID*FFD, i_f2b, si*HID,
          i_l2g, si*HID, i_l2b, si*HID, flag);
      k_ffln<1><<<BB*NN*SEGN/FFROWS, 512, 0, stream>>>(z,
          i_f1w, si*FFD*HID, i_f1b, si*FFD, i_f2w, si*HID*FFD, i_f2b, si*HID,
          i_l2g, si*HID, i_l2b, si*HID, flag);
      k_gqkv<0><<<16*NN, 128, 0, stream>>>(z,
          i_gwq, si*DKK*HID, i_gwk, si*DKK*HID, i_gwv, si*HID*HID, qb, kb, vb, flag);
      k_gqkv<1><<<16*NN, 128, 0, stream>>>(z,
          i_gwq, si*DKK*HID, i_gwk, si*DKK*HID, i_gwv, si*HID*HID, qb, kb, vb, flag);
      k_gattn<<<16*(NN/QB), 256, 0, stream>>>(z, qb, kb, vb,
          i_gl1g, si*HID, i_gl1b, si*HID, flag);
      k_ffln<0><<<BB*NN*SEGN/FFROWS, 512, 0, stream>>>(z,
          i_gf1w, si*FFD*HID, i_gf1b, si*FFD, i_gf2w, si*HID*FFD, i_gf2b, si*HID,
          i_gl2g, si*HID, i_gl2b, si*HID, flag);
      k_ffln<1><<<BB*NN*SEGN/FFROWS, 512, 0, stream>>>(z,
          i_gf1w, si*FFD*HID, i_gf1b, si*FFD, i_gf2w, si*HID*FFD, i_gf2b, si*HID,
          i_gl2g, si*HID, i_gl2b, si*HID, flag);
    }
    k_pool<<<BB*NN, 64, 0, stream>>>(z, enc, s);
  }
  k_fqkv<0><<<BB*NN, 128, 0, stream>>>(enc, i_cwq, i_cwk, i_cwv, qb, kb, vb, flag);
  k_fqkv<1><<<BB*NN, 128, 0, stream>>>(enc, i_cwq, i_cwk, i_cwv, qb, kb, vb, flag);
  k_fattn<<<BB*(NN/QB), 256, 0, stream>>>(qb, kb, vb, d_out, flag);
}

// Round 4
// 2774.876 us; speedup vs baseline: 2.7451x; 2.7451x over previous
//
#include <hip/hip_runtime.h>
#include <hip/hip_bf16.h>
#include <math.h>

// Problem constants
#define BB 4
#define SEQL 12
#define NN 1024
#define SEGL 3
#define SEGN 4
#define HID 64
#define FFD 2048
#define DKK 32
#define NHH 8
#define HDD 8

using bf16 = __hip_bfloat16;
__device__ __forceinline__ float b2f(bf16 v) { return __bfloat162float(v); }

typedef __attribute__((ext_vector_type(8))) short s8v;   // 8 bf16 (4 VGPRs)
typedef __attribute__((ext_vector_type(4))) float f4v;   // MFMA C/D

__device__ __forceinline__ unsigned short f2b(float f) {
  bf16 h = __float2bfloat16(f);
  unsigned short u; __builtin_memcpy(&u, &h, 2); return u;
}

// dtype-templated weight load: F=1 fp32 storage, F=0 bf16 storage
template <int F>
__device__ __forceinline__ float ldw(const void* p, long i) {
  if (F) return ((const float*)p)[i];
  return b2f(((const bf16*)p)[i]);
}

// 8-element bf16 fragment load from weight array at element offset (multiple of 8)
template <int F>
__device__ __forceinline__ s8v ldfrag(const void* p, long elemOff) {
  if (F) {
    const float* fp = (const float*)p + elemOff;
    f4v u = *(const f4v*)fp, v = *(const f4v*)(fp + 4);
    s8v t;
    t[0]=f2b(u[0]); t[1]=f2b(u[1]); t[2]=f2b(u[2]); t[3]=f2b(u[3]);
    t[4]=f2b(v[0]); t[5]=f2b(v[1]); t[6]=f2b(v[2]); t[7]=f2b(v[3]);
    return t;
  }
  return *(const s8v*)((const unsigned short*)p + elemOff);
}

// ---------------------------------------------------------------- zero-fill d_out (guard path)
__global__ void k_zero(unsigned short* __restrict__ o, int n) {
  int i = blockIdx.x * 256 + threadIdx.x;
  if (i < n) o[i] = 0;
}

// ---------------------------------------------------------------- detect dtype
__global__ void k_detect(const void* __restrict__ x0, int* __restrict__ flag) {
  int t = threadIdx.x;
  int bad = 0;
  const bf16* p = (const bf16*)x0;
  for (int i = t; i < 512; i += 256) {
    float a = fabsf(b2f(p[i]));
    if (!(a < 1e4f) || (a != 0.f && a < 1e-4f)) bad = 1;
  }
  __shared__ int tot;
  if (t == 0) tot = 0;
  __syncthreads();
  unsigned long long m = __ballot(bad);
  if ((t & 63) == 0) atomicAdd(&tot, __popcll(m));
  __syncthreads();
  if (t == 0) *flag = (tot > 64) ? 1 : 0;   // 1 = fp32 storage, 0 = bf16
}

// ---------------------------------------------------------------- patch embed
template <int F>
__global__ __launch_bounds__(256) void k_patch(const void* __restrict__ x,
    const void* __restrict__ pw, long opw, const void* __restrict__ pb, long opb,
    float* __restrict__ z, const int* __restrict__ flag) {
  if (*flag != F) return;
  int b = blockIdx.x >> 10, n = blockIdx.x & 1023;
  int g = threadIdx.x >> 6, h = threadIdx.x & 63;
  float acc = ldw<F>(pb, opb + h);
#pragma unroll
  for (int l = 0; l < SEGL; ++l)
    acc += ldw<F>(x, (long)(b*SEQL + g*SEGL + l)*NN + n) * ldw<F>(pw, opw + h*SEGL + l);
  int i2 = h >> 1;
  float dv = expf((float)(2*i2) * (-logf(10000.f) / (float)HID));
  float ang = (float)g * dv;
  acc += (h & 1) ? cosf(ang) : sinf(ang);
  z[((long)(b*NN + n)*SEGN + g)*HID + h] = acc;
}

// ---------------------------------------------------------------- temporal MHA + LN1
template <int F>
__global__ __launch_bounds__(64) void k_tattn(float* __restrict__ z,
    const void* __restrict__ W, long oW, const void* __restrict__ bqkv, long obq,
    const void* __restrict__ WO, long oWO, const void* __restrict__ bo, long obo,
    const void* __restrict__ g1, long og1, const void* __restrict__ b1, long ob1,
    const int* __restrict__ flag) {
  if (*flag != F) return;
  __shared__ float xr[SEGN][HID];
  __shared__ float qkv[SEGN][3*HID];
  __shared__ float ao[SEGN][HID];
  __shared__ float mst[SEGN][2];
  int h = threadIdx.x;
  float* zp = z + (long)blockIdx.x * SEGN * HID;
#pragma unroll
  for (int g = 0; g < SEGN; ++g) xr[g][h] = zp[g*HID + h];
  __syncthreads();
#pragma unroll
  for (int j = 0; j < 3; ++j) {
    int c = j*HID + h;
    long wr = oW + (long)c*HID;
    float a0=0,a1=0,a2=0,a3=0;
    for (int k = 0; k < HID; ++k) {
      float w = ldw<F>(W, wr + k);
      a0 += xr[0][k]*w; a1 += xr[1][k]*w; a2 += xr[2][k]*w; a3 += xr[3][k]*w;
    }
    float bb = ldw<F>(bqkv, obq + c);
    qkv[0][c]=a0+bb; qkv[1][c]=a1+bb; qkv[2][c]=a2+bb; qkv[3][c]=a3+bb;
  }
  __syncthreads();
  if (h < NHH*SEGN) {
    int head = h >> 2, qt = h & 3;
    const float scale = 0.3535533905932738f;   // 1/sqrt(8)
    float s[SEGN]; float mx = -1e30f;
#pragma unroll
    for (int kt = 0; kt < SEGN; ++kt) {
      float d = 0;
#pragma unroll
      for (int e = 0; e < HDD; ++e) d += qkv[qt][head*HDD+e]*qkv[kt][HID+head*HDD+e];
      s[kt] = d*scale; mx = fmaxf(mx, s[kt]);
    }
    float se = 0;
#pragma unroll
    for (int kt = 0; kt < SEGN; ++kt) { s[kt] = expf(s[kt]-mx); se += s[kt]; }
    float inv = 1.f/se;
#pragma unroll
    for (int e = 0; e < HDD; ++e) {
      float o = 0;
#pragma unroll
      for (int kt = 0; kt < SEGN; ++kt) o += s[kt]*qkv[kt][2*HID+head*HDD+e];
      ao[qt][head*HDD+e] = o*inv;
    }
  }
  __syncthreads();
  float y[SEGN];
  {
    long wr = oWO + (long)h*HID;
    float bb = ldw<F>(bo, obo + h);
#pragma unroll
    for (int g = 0; g < SEGN; ++g) {
      float a = bb;
      for (int k = 0; k < HID; ++k) a += ao[g][k]*ldw<F>(WO, wr + k);
      y[g] = xr[g][h] + a;    // residual
    }
  }
  __syncthreads();
#pragma unroll
  for (int g = 0; g < SEGN; ++g) xr[g][h] = y[g];
  __syncthreads();
  if (h < SEGN) {
    float m = 0;
    for (int k = 0; k < HID; ++k) m += xr[h][k];
    m *= (1.f/HID);
    float v = 0;
    for (int k = 0; k < HID; ++k) { float d = xr[h][k]-m; v += d*d; }
    mst[h][0] = m; mst[h][1] = rsqrtf(v*(1.f/HID) + 1e-5f);
  }
  __syncthreads();
  float gg = ldw<F>(g1, og1 + h), bb2 = ldw<F>(b1, ob1 + h);
#pragma unroll
  for (int g = 0; g < SEGN; ++g)
    zp[g*HID + h] = (y[g]-mst[g][0])*mst[g][1]*gg + bb2;
}

// ---------------------------------------------------------------- FF via MFMA bf16
// out = LN(x + relu(x@W1^T+B1)@W2^T+B2) on rows of 64 features.
// Block: 32 rows, 256 threads (4 waves). Hidden dim streamed in 256-chunks.
// GEMM1: A = X rows (fp32->bf16 regs), B = W1 rows (K-contiguous, direct 16B loads).
// Hc round-trips LDS (C-layout -> A-layout). GEMM2 accumulates fp32 across chunks.
// Fragment maps (m89/m91/m120-verified): A: m=lane&15,k=quad*8+j; B: n=lane&15,
// k=quad*8+j; C/D: col=lane&15,row=quad*4+reg.
#define RT 32
#define JT 256
template <int F>
__global__ __launch_bounds__(256) void k_ffmfma(float* __restrict__ x,
    const void* __restrict__ W1, long o1, const void* __restrict__ B1, long ob1,
    const void* __restrict__ W2, long o2, const void* __restrict__ B2, long ob2,
    const void* __restrict__ G, long og, const void* __restrict__ Bt, long obt,
    const int* __restrict__ flag) {
  if (*flag != F) return;
  __shared__ unsigned short hc[RT][JT + 8];   // row stride 264 us = 528 B (16B-aligned)
  __shared__ float yb[RT][66];
  int tid = threadIdx.x;
  int w = tid >> 6, lane = tid & 63;
  int col = lane & 15, quad = lane >> 4;
  int mt = w & 1, grp = w >> 1;
  long r0 = (long)blockIdx.x * RT;

  // A1 fragments: this wave's M-tile rows of X, bf16 (constant across chunks)
  s8v a1[2];
  {
    const float* xr = x + (r0 + mt*16 + col) * HID;
#pragma unroll
    for (int ks = 0; ks < 2; ++ks) {
      const float* p = xr + ks*32 + quad*8;
      f4v u = *(const f4v*)p, v = *(const f4v*)(p + 4);
      s8v t;
      t[0]=f2b(u[0]); t[1]=f2b(u[1]); t[2]=f2b(u[2]); t[3]=f2b(u[3]);
      t[4]=f2b(v[0]); t[5]=f2b(v[1]); t[6]=f2b(v[2]); t[7]=f2b(v[3]);
      a1[ks] = t;
    }
  }

  f4v acc[2];
  acc[0] = (f4v){0.f,0.f,0.f,0.f};
  acc[1] = (f4v){0.f,0.f,0.f,0.f};

  for (int j0 = 0; j0 < FFD; j0 += JT) {
    // ---- GEMM1: Hc = relu(X @ W1c^T + B1); wave covers M-tile mt, N-tiles grp*8..+7
    f4v h[8];
#pragma unroll
    for (int t = 0; t < 8; ++t) h[t] = (f4v){0.f,0.f,0.f,0.f};
#pragma unroll
    for (int t = 0; t < 8; ++t) {
      long j = j0 + (grp*8 + t)*16 + col;           // this lane's B-frag column (hidden idx)
#pragma unroll
      for (int ks = 0; ks < 2; ++ks) {
        s8v b = ldfrag<F>(W1, o1 + j*HID + ks*32 + quad*8);
        h[t] = __builtin_amdgcn_mfma_f32_16x16x32_bf16(a1[ks], b, h[t], 0, 0, 0);
      }
    }
    __syncthreads();                               // previous chunk's GEMM2 reads done
#pragma unroll
    for (int t = 0; t < 8; ++t) {
      int jc = (grp*8 + t)*16 + col;
      float b1v = ldw<F>(B1, ob1 + j0 + jc);
      int row0 = mt*16 + quad*4;
#pragma unroll
      for (int r = 0; r < 4; ++r)
        hc[row0 + r][jc] = f2b(fmaxf(h[t][r] + b1v, 0.f));
    }
    __syncthreads();
    // ---- GEMM2: acc += Hc @ W2c^T; wave covers M-tile mt, N-tiles grp*2, grp*2+1
#pragma unroll
    for (int kk = 0; kk < 8; ++kk) {
      s8v a = *(const s8v*)&hc[mt*16 + col][kk*32 + quad*8];
#pragma unroll
      for (int t = 0; t < 2; ++t) {
        long c = (grp*2 + t)*16 + col;
        s8v b = ldfrag<F>(W2, o2 + c*FFD + j0 + kk*32 + quad*8);
        acc[t] = __builtin_amdgcn_mfma_f32_16x16x32_bf16(a, b, acc[t], 0, 0, 0);
      }
    }
  }

  // ---- epilogue: +B2 -> LDS, then residual + LN per row
#pragma unroll
  for (int t = 0; t < 2; ++t) {
    int c = (grp*2 + t)*16 + col;
    float b2v = ldw<F>(B2, ob2 + c);
    int row0 = mt*16 + quad*4;
#pragma unroll
    for (int r = 0; r < 4; ++r)
      yb[row0 + r][c] = acc[t][r] + b2v;
  }
  __syncthreads();
  float gg = ldw<F>(G, og + lane), bbt = ldw<F>(Bt, obt + lane);
#pragma unroll
  for (int rr = 0; rr < 8; ++rr) {
    int rl = w*8 + rr;
    long grow = r0 + rl;
    float val = yb[rl][lane] + x[grow*HID + lane];
    float s = val;
#pragma unroll
    for (int off = 32; off; off >>= 1) s += __shfl_xor(s, off);
    float m = s * (1.f/HID);
    float d = val - m;
    float sq = d*d;
#pragma unroll
    for (int off = 32; off; off >>= 1) sq += __shfl_xor(sq, off);
    float rv = rsqrtf(sq*(1.f/HID) + 1e-5f);
    x[grow*HID + lane] = d*rv*gg + bbt;
  }
}

// ---------------------------------------------------------------- graph qkv proj
template <int F>
__global__ __launch_bounds__(128) void k_gqkv(const float* __restrict__ z,
    const void* __restrict__ wq, long oq, const void* __restrict__ wk, long ok,
    const void* __restrict__ wv, long ov,
    float* __restrict__ q, float* __restrict__ k, float* __restrict__ v,
    const int* __restrict__ flag) {
  if (*flag != F) return;
  __shared__ float xs[HID];
  int bg = blockIdx.x >> 10, n = blockIdx.x & 1023;
  int b = bg >> 2, g = bg & 3;
  const float* zp = z + ((long)(b*NN + n)*SEGN + g)*HID;
  int t = threadIdx.x;
  if (t < HID) xs[t] = zp[t];
  __syncthreads();
  long r = (long)bg*NN + n;
  if (t < 32) {
    long wr = oq + (long)t*HID; float a = 0;
    for (int e = 0; e < HID; ++e) a += xs[e]*ldw<F>(wq, wr + e);
    q[r*DKK + t] = a;
  } else if (t < 64) {
    long wr = ok + (long)(t-32)*HID; float a = 0;
    for (int e = 0; e < HID; ++e) a += xs[e]*ldw<F>(wk, wr + e);
    k[r*DKK + (t-32)] = a;
  } else {
    long wr = ov + (long)(t-64)*HID; float a = 0;
    for (int e = 0; e < HID; ++e) a += xs[e]*ldw<F>(wv, wr + e);
    v[r*HID + (t-64)] = a;
  }
}

// ---------------------------------------------------------------- graph attention
#define QB 8
#define TM 64
__global__ __launch_bounds__(256) void k_gattn(float* __restrict__ z,
    const float* __restrict__ q, const float* __restrict__ k,
    const float* __restrict__ v,
    const void* __restrict__ g1, long og1, const void* __restrict__ b1, long ob1,
    const int* __restrict__ flag) {
  int f = *flag;
  __shared__ float qs[QB][DKK];
  __shared__ float sc[QB][NN];
  __shared__ float tile[TM*66];
  __shared__ float oacc[QB][HID];
  int tid = threadIdx.x;
  int wave = tid >> 6, lane = tid & 63;
  int bg = blockIdx.x >> 7;
  int n0 = (blockIdx.x & 127) * QB;
  if (tid < QB*DKK)
    qs[tid >> 5][tid & 31] = q[((long)bg*NN + n0 + (tid >> 5))*DKK + (tid & 31)];
  __syncthreads();
  const float rs = 0.17677669529663687f;   // 1/sqrt(32)
  for (int m0 = 0; m0 < NN; m0 += TM) {
    for (int i = tid; i < TM*DKK; i += 256)
      tile[(i >> 5)*33 + (i & 31)] = k[((long)bg*NN + m0)*DKK + i];
    __syncthreads();
    for (int tt = tid; tt < QB*TM; tt += 256) {
      int qq = tt >> 6, mm = tt & 63;
      const float* kt = &tile[mm*33];
      const float* qp = qs[qq];
      float a = 0;
#pragma unroll
      for (int e = 0; e < DKK; ++e) a += qp[e]*kt[e];
      sc[qq][m0 + mm] = a*rs;
    }
    __syncthreads();
  }
  for (int qq = wave*2; qq < wave*2 + 2; ++qq) {
    float mx = -1e30f;
    for (int mm = lane; mm < NN; mm += 64) mx = fmaxf(mx, sc[qq][mm]);
#pragma unroll
    for (int off = 32; off; off >>= 1) mx = fmaxf(mx, __shfl_xor(mx, off));
    float se = 0;
    for (int mm = lane; mm < NN; mm += 64) { float e = expf(sc[qq][mm]-mx); sc[qq][mm] = e; se += e; }
#pragma unroll
    for (int off = 32; off; off >>= 1) se += __shfl_xor(se, off);
    float inv = 1.f/se;
    for (int mm = lane; mm < NN; mm += 64) sc[qq][mm] *= inv;
  }
  for (int i = tid; i < QB*HID; i += 256) oacc[i >> 6][i & 63] = 0.f;
  __syncthreads();
  for (int m0 = 0; m0 < NN; m0 += TM) {
    for (int i = tid; i < TM*HID; i += 256)
      tile[i] = v[((long)bg*NN + m0)*HID + i];
    __syncthreads();
    for (int tt = tid; tt < QB*HID; tt += 256) {
      int qq = tt >> 6, hh = tt & 63;
      float a = oacc[qq][hh];
      const float* sp = &sc[qq][m0];
      for (int mm = 0; mm < TM; ++mm) a += sp[mm]*tile[mm*HID + hh];
      oacc[qq][hh] = a;
    }
    __syncthreads();
  }
  int b = bg >> 2, g = bg & 3;
  float gg = f ? ((const float*)g1)[og1 + lane] : b2f(((const bf16*)g1)[og1 + lane]);
  float bb = f ? ((const float*)b1)[ob1 + lane] : b2f(((const bf16*)b1)[ob1 + lane]);
  for (int qq = wave*2; qq < wave*2 + 2; ++qq) {
    float val = oacc[qq][lane];
    float s = val;
#pragma unroll
    for (int off = 32; off; off >>= 1) s += __shfl_xor(s, off);
    float m = s*(1.f/HID);
    float d = val - m, sq = d*d;
#pragma unroll
    for (int off = 32; off; off >>= 1) sq += __shfl_xor(sq, off);
    float r = rsqrtf(sq*(1.f/HID) + 1e-5f);
    float* zp = z + ((long)(b*NN + n0 + qq)*SEGN + g)*HID;
    zp[lane] = d*r*gg + bb + zp[lane];   // LN(att) + x
  }
}

// ---------------------------------------------------------------- pool over segments
__global__ __launch_bounds__(64) void k_pool(const float* __restrict__ z,
    float* __restrict__ enc, int s) {
  int b = blockIdx.x >> 10, n = blockIdx.x & 1023, h = threadIdx.x;
  const float* zp = z + (long)(b*NN + n)*SEGN*HID;
  float a = 0;
#pragma unroll
  for (int g = 0; g < SEGN; ++g) a += zp[g*HID + h];
  enc[(long)(b*NN + n)*(2*HID) + s*HID + h] = a*0.25f;
}

// ---------------------------------------------------------------- final qkv proj (in_dim=128)
template <int F>
__global__ __launch_bounds__(128) void k_fqkv(const float* __restrict__ enc,
    const void* __restrict__ wq, const void* __restrict__ wk,
    const void* __restrict__ wv,
    float* __restrict__ q, float* __restrict__ k, float* __restrict__ v,
    const int* __restrict__ flag) {
  if (*flag != F) return;
  __shared__ float xs[2*HID];
  long r = blockIdx.x;
  int t = threadIdx.x;
  xs[t] = enc[r*128 + t];
  __syncthreads();
  if (t < 32) {
    long wr = (long)t*128; float a = 0;
    for (int e = 0; e < 128; ++e) a += xs[e]*ldw<F>(wq, wr + e);
    q[r*DKK + t] = a;
  } else if (t < 64) {
    long wr = (long)(t-32)*128; float a = 0;
    for (int e = 0; e < 128; ++e) a += xs[e]*ldw<F>(wk, wr + e);
    k[r*DKK + (t-32)] = a;
  } else {
    long wr = (long)(t-64)*128; float a = 0;
    for (int e = 0; e < 128; ++e) a += xs[e]*ldw<F>(wv, wr + e);
    v[r*HID + (t-64)] = a;
  }
}

// ---------------------------------------------------------------- final attention -> d_out
__global__ __launch_bounds__(256) void k_fattn(const float* __restrict__ q,
    const float* __restrict__ k, const float* __restrict__ v,
    void* __restrict__ outp, const int* __restrict__ flag) {
  __shared__ float qs[QB][DKK];
  __shared__ float sc[QB][NN];
  __shared__ float tile[TM*66];
  __shared__ float oacc[QB][HID];
  int tid = threadIdx.x;
  int wave = tid >> 6, lane = tid & 63;
  int b = blockIdx.x >> 7;
  int n0 = (blockIdx.x & 127) * QB;
  if (tid < QB*DKK)
    qs[tid >> 5][tid & 31] = q[((long)b*NN + n0 + (tid >> 5))*DKK + (tid & 31)];
  __syncthreads();
  const float rs = 0.17677669529663687f;
  for (int m0 = 0; m0 < NN; m0 += TM) {
    for (int i = tid; i < TM*DKK; i += 256)
      tile[(i >> 5)*33 + (i & 31)] = k[((long)b*NN + m0)*DKK + i];
    __syncthreads();
    for (int tt = tid; tt < QB*TM; tt += 256) {
      int qq = tt >> 6, mm = tt & 63;
      const float* kt = &tile[mm*33];
      const float* qp = qs[qq];
      float a = 0;
#pragma unroll
      for (int e = 0; e < DKK; ++e) a += qp[e]*kt[e];
      sc[qq][m0 + mm] = a*rs;
    }
    __syncthreads();
  }
  for (int qq = wave*2; qq < wave*2 + 2; ++qq) {
    float mx = -1e30f;
    for (int mm = lane; mm < NN; mm += 64) mx = fmaxf(mx, sc[qq][mm]);
#pragma unroll
    for (int off = 32; off; off >>= 1) mx = fmaxf(mx, __shfl_xor(mx, off));
    float se = 0;
    for (int mm = lane; mm < NN; mm += 64) { float e = expf(sc[qq][mm]-mx); sc[qq][mm] = e; se += e; }
#pragma unroll
    for (int off = 32; off; off >>= 1) se += __shfl_xor(se, off);
    float inv = 1.f/se;
    for (int mm = lane; mm < NN; mm += 64) sc[qq][mm] *= inv;
  }
  for (int i = tid; i < QB*HID; i += 256) oacc[i >> 6][i & 63] = 0.f;
  __syncthreads();
  for (int m0 = 0; m0 < NN; m0 += TM) {
    for (int i = tid; i < TM*HID; i += 256)
      tile[i] = v[((long)b*NN + m0)*HID + i];
    __syncthreads();
    for (int tt = tid; tt < QB*HID; tt += 256) {
      int qq = tt >> 6, hh = tt & 63;
      float a = oacc[qq][hh];
      const float* sp = &sc[qq][m0];
      for (int mm = 0; mm < TM; ++mm) a += sp[mm]*tile[mm*HID + hh];
      oacc[qq][hh] = a;
    }
    __syncthreads();
  }
  int f = *flag;
  for (int qq = wave*2; qq < wave*2 + 2; ++qq) {
    float val = oacc[qq][lane];
    long idx = ((long)(b*NN + n0 + qq))*HID + lane;
    if (f) ((float*)outp)[idx] = val;
    else   ((bf16*)outp)[idx] = __float2bfloat16(val);
  }
}

// ================================================================ launch
extern "C" void kernel_launch(void* const* d_in, const int* in_sizes, int n_in,
                              void* d_out, int out_size, void* d_ws, size_t ws_size,
                              hipStream_t stream) {
  static const int EXP[30] = {
    49152, 49152, 384, 128, 49152, 768, 16384, 256,
    524288, 8192, 524288, 256, 256, 256, 256, 256,
    8192, 8192, 16384, 524288, 8192, 524288, 256, 256,
    256, 256, 256, 4096, 4096, 8192
  };
  const size_t NEED = (size_t)(1048576 + 524288 + 524288 + 524288 + 1048576) * 4 + 64;
  bool ok = (n_in == 30) && (ws_size >= NEED) && (out_size == BB*NN*HID);
  if (ok) for (int i = 0; i < 30; ++i) ok = ok && (in_sizes[i] == EXP[i]);
  if (!ok) {
    k_zero<<<(BB*NN*HID + 255)/256, 256, 0, stream>>>((unsigned short*)d_out, BB*NN*HID);
    return;
  }

  float* z   = (float*)d_ws;             // [4,1024,4,64]
  float* enc = z   + 1048576;            // [4,1024,128]
  float* qb  = enc + 524288;             // [16,1024,32]
  float* kb  = qb  + 524288;             // [16,1024,32]
  float* vb  = kb  + 524288;             // [16,1024,64]
  int*  flag = (int*)(vb + 1048576);

  k_detect<<<1, 256, 0, stream>>>(d_in[0], flag);

  const void *i_traffic=d_in[0], *i_user=d_in[1], *i_pw=d_in[2], *i_pb=d_in[3],
    *i_mw=d_in[4], *i_mb=d_in[5], *i_ow=d_in[6], *i_ob=d_in[7], *i_f1w=d_in[8],
    *i_f1b=d_in[9], *i_f2w=d_in[10], *i_f2b=d_in[11], *i_l1g=d_in[12],
    *i_l1b=d_in[13], *i_l2g=d_in[14], *i_l2b=d_in[15], *i_gwq=d_in[16],
    *i_gwk=d_in[17], *i_gwv=d_in[18], *i_gf1w=d_in[19], *i_gf1b=d_in[20],
    *i_gf2w=d_in[21], *i_gf2b=d_in[22], *i_gl1g=d_in[23], *i_gl1b=d_in[24],
    *i_gl2g=d_in[25], *i_gl2b=d_in[26], *i_cwq=d_in[27], *i_cwk=d_in[28],
    *i_cwv=d_in[29];

  const int FFG = BB*NN*SEGN/RT;         // 512 blocks

  for (int s = 0; s < 2; ++s) {
    const void* x = s ? i_user : i_traffic;
    k_patch<0><<<BB*NN, 256, 0, stream>>>(x, i_pw, (long)s*HID*SEGL, i_pb, (long)s*HID, z, flag);
    k_patch<1><<<BB*NN, 256, 0, stream>>>(x, i_pw, (long)s*HID*SEGL, i_pb, (long)s*HID, z, flag);
    for (int i = 0; i < 2; ++i) {
      long si = s*2 + i;
      k_tattn<0><<<BB*NN, 64, 0, stream>>>(z,
          i_mw, si*3*HID*HID, i_mb, si*3*HID, i_ow, si*HID*HID, i_ob, si*HID,
          i_l1g, si*HID, i_l1b, si*HID, flag);
      k_tattn<1><<<BB*NN, 64, 0, stream>>>(z,
          i_mw, si*3*HID*HID, i_mb, si*3*HID, i_ow, si*HID*HID, i_ob, si*HID,
          i_l1g, si*HID, i_l1b, si*HID, flag);
      k_ffmfma<0><<<FFG, 256, 0, stream>>>(z,
          i_f1w, si*FFD*HID, i_f1b, si*FFD, i_f2w, si*HID*FFD, i_f2b, si*HID,
          i_l2g, si*HID, i_l2b, si*HID, flag);
      k_ffmfma<1><<<FFG, 256, 0, stream>>>(z,
          i_f1w, si*FFD*HID, i_f1b, si*FFD, i_f2w, si*HID*FFD, i_f2b, si*HID,
          i_l2g, si*HID, i_l2b, si*HID, flag);
      k_gqkv<0><<<16*NN, 128, 0, stream>>>(z,
          i_gwq, si*DKK*HID, i_gwk, si*DKK*HID, i_gwv, si*HID*HID, qb, kb, vb, flag);
      k_gqkv<1><<<16*NN, 128, 0, stream>>>(z,
          i_gwq, si*DKK*HID, i_gwk, si*DKK*HID, i_gwv, si*HID*HID, qb, kb, vb, flag);
      k_gattn<<<16*(NN/QB), 256, 0, stream>>>(z, qb, kb, vb,
          i_gl1g, si*HID, i_gl1b, si*HID, flag);
      k_ffmfma<0><<<FFG, 256, 0, stream>>>(z,
          i_gf1w, si*FFD*HID, i_gf1b, si*FFD, i_gf2w, si*HID*FFD, i_gf2b, si*HID,
          i_gl2g, si*HID, i_gl2b, si*HID, flag);
      k_ffmfma<1><<<FFG, 256, 0, stream>>>(z,
          i_gf1w, si*FFD*HID, i_gf1b, si*FFD, i_gf2w, si*HID*FFD, i_gf2b, si*HID,
          i_gl2g, si*HID, i_gl2b, si*HID, flag);
    }
    k_pool<<<BB*NN, 64, 0, stream>>>(z, enc, s);
  }
  k_fqkv<0><<<BB*NN, 128, 0, stream>>>(enc, i_cwq, i_cwk, i_cwv, qb, kb, vb, flag);
  k_fqkv<1><<<BB*NN, 128, 0, stream>>>(enc, i_cwq, i_cwk, i_cwv, qb, kb, vb, flag);
  k_fattn<<<BB*(NN/QB), 256, 0, stream>>>(qb, kb, vb, d_out, flag);
}

// Round 5
// 2051.263 us; speedup vs baseline: 3.7135x; 1.3528x over previous
//
#include <hip/hip_runtime.h>
#include <hip/hip_bf16.h>
#include <math.h>

// Problem constants
#define BB 4
#define SEQL 12
#define NN 1024
#define SEGL 3
#define SEGN 4
#define HID 64
#define FFD 2048
#define DKK 32
#define NHH 8
#define HDD 8

using bf16 = __hip_bfloat16;
__device__ __forceinline__ float b2f(bf16 v) { return __bfloat162float(v); }

typedef __attribute__((ext_vector_type(8))) short s8v;   // 8 bf16 (4 VGPRs)
typedef __attribute__((ext_vector_type(4))) float f4v;   // MFMA C/D

__device__ __forceinline__ unsigned short f2b(float f) {
  bf16 h = __float2bfloat16(f);
  unsigned short u; __builtin_memcpy(&u, &h, 2); return u;
}

// dtype-templated weight load: F=1 fp32 storage, F=0 bf16 storage
template <int F>
__device__ __forceinline__ float ldw(const void* p, long i) {
  if (F) return ((const float*)p)[i];
  return b2f(((const bf16*)p)[i]);
}

// 8-element bf16 fragment load from weight array at element offset (multiple of 8)
template <int F>
__device__ __forceinline__ s8v ldfrag(const void* p, long elemOff) {
  if (F) {
    const float* fp = (const float*)p + elemOff;
    f4v u = *(const f4v*)fp, v = *(const f4v*)(fp + 4);
    s8v t;
    t[0]=f2b(u[0]); t[1]=f2b(u[1]); t[2]=f2b(u[2]); t[3]=f2b(u[3]);
    t[4]=f2b(v[0]); t[5]=f2b(v[1]); t[6]=f2b(v[2]); t[7]=f2b(v[3]);
    return t;
  }
  return *(const s8v*)((const unsigned short*)p + elemOff);
}

// ---------------------------------------------------------------- zero-fill d_out (guard path)
__global__ void k_zero(unsigned short* __restrict__ o, int n) {
  int i = blockIdx.x * 256 + threadIdx.x;
  if (i < n) o[i] = 0;
}

// ---------------------------------------------------------------- detect dtype
__global__ void k_detect(const void* __restrict__ x0, int* __restrict__ flag) {
  int t = threadIdx.x;
  int bad = 0;
  const bf16* p = (const bf16*)x0;
  for (int i = t; i < 512; i += 256) {
    float a = fabsf(b2f(p[i]));
    if (!(a < 1e4f) || (a != 0.f && a < 1e-4f)) bad = 1;
  }
  __shared__ int tot;
  if (t == 0) tot = 0;
  __syncthreads();
  unsigned long long m = __ballot(bad);
  if ((t & 63) == 0) atomicAdd(&tot, __popcll(m));
  __syncthreads();
  if (t == 0) *flag = (tot > 64) ? 1 : 0;   // 1 = fp32 storage, 0 = bf16
}

// ---------------------------------------------------------------- patch embed
template <int F>
__global__ __launch_bounds__(256) void k_patch(const void* __restrict__ x,
    const void* __restrict__ pw, long opw, const void* __restrict__ pb, long opb,
    float* __restrict__ z, const int* __restrict__ flag) {
  if (*flag != F) return;
  int b = blockIdx.x >> 10, n = blockIdx.x & 1023;
  int g = threadIdx.x >> 6, h = threadIdx.x & 63;
  float acc = ldw<F>(pb, opb + h);
#pragma unroll
  for (int l = 0; l < SEGL; ++l)
    acc += ldw<F>(x, (long)(b*SEQL + g*SEGL + l)*NN + n) * ldw<F>(pw, opw + h*SEGL + l);
  int i2 = h >> 1;
  float dv = expf((float)(2*i2) * (-logf(10000.f) / (float)HID));
  float ang = (float)g * dv;
  acc += (h & 1) ? cosf(ang) : sinf(ang);
  z[((long)(b*NN + n)*SEGN + g)*HID + h] = acc;
}

// ---------------------------------------------------------------- temporal MHA + LN1
template <int F>
__global__ __launch_bounds__(64) void k_tattn(float* __restrict__ z,
    const void* __restrict__ W, long oW, const void* __restrict__ bqkv, long obq,
    const void* __restrict__ WO, long oWO, const void* __restrict__ bo, long obo,
    const void* __restrict__ g1, long og1, const void* __restrict__ b1, long ob1,
    const int* __restrict__ flag) {
  if (*flag != F) return;
  __shared__ float xr[SEGN][HID];
  __shared__ float qkv[SEGN][3*HID];
  __shared__ float ao[SEGN][HID];
  __shared__ float mst[SEGN][2];
  int h = threadIdx.x;
  float* zp = z + (long)blockIdx.x * SEGN * HID;
#pragma unroll
  for (int g = 0; g < SEGN; ++g) xr[g][h] = zp[g*HID + h];
  __syncthreads();
#pragma unroll
  for (int j = 0; j < 3; ++j) {
    int c = j*HID + h;
    long wr = oW + (long)c*HID;
    float a0=0,a1=0,a2=0,a3=0;
    for (int k = 0; k < HID; ++k) {
      float w = ldw<F>(W, wr + k);
      a0 += xr[0][k]*w; a1 += xr[1][k]*w; a2 += xr[2][k]*w; a3 += xr[3][k]*w;
    }
    float bb = ldw<F>(bqkv, obq + c);
    qkv[0][c]=a0+bb; qkv[1][c]=a1+bb; qkv[2][c]=a2+bb; qkv[3][c]=a3+bb;
  }
  __syncthreads();
  if (h < NHH*SEGN) {
    int head = h >> 2, qt = h & 3;
    const float scale = 0.3535533905932738f;   // 1/sqrt(8)
    float s[SEGN]; float mx = -1e30f;
#pragma unroll
    for (int kt = 0; kt < SEGN; ++kt) {
      float d = 0;
#pragma unroll
      for (int e = 0; e < HDD; ++e) d += qkv[qt][head*HDD+e]*qkv[kt][HID+head*HDD+e];
      s[kt] = d*scale; mx = fmaxf(mx, s[kt]);
    }
    float se = 0;
#pragma unroll
    for (int kt = 0; kt < SEGN; ++kt) { s[kt] = expf(s[kt]-mx); se += s[kt]; }
    float inv = 1.f/se;
#pragma unroll
    for (int e = 0; e < HDD; ++e) {
      float o = 0;
#pragma unroll
      for (int kt = 0; kt < SEGN; ++kt) o += s[kt]*qkv[kt][2*HID+head*HDD+e];
      ao[qt][head*HDD+e] = o*inv;
    }
  }
  __syncthreads();
  float y[SEGN];
  {
    long wr = oWO + (long)h*HID;
    float bb = ldw<F>(bo, obo + h);
#pragma unroll
    for (int g = 0; g < SEGN; ++g) {
      float a = bb;
      for (int k = 0; k < HID; ++k) a += ao[g][k]*ldw<F>(WO, wr + k);
      y[g] = xr[g][h] + a;    // residual
    }
  }
  __syncthreads();
#pragma unroll
  for (int g = 0; g < SEGN; ++g) xr[g][h] = y[g];
  __syncthreads();
  if (h < SEGN) {
    float m = 0;
    for (int k = 0; k < HID; ++k) m += xr[h][k];
    m *= (1.f/HID);
    float v = 0;
    for (int k = 0; k < HID; ++k) { float d = xr[h][k]-m; v += d*d; }
    mst[h][0] = m; mst[h][1] = rsqrtf(v*(1.f/HID) + 1e-5f);
  }
  __syncthreads();
  float gg = ldw<F>(g1, og1 + h), bb2 = ldw<F>(b1, ob1 + h);
#pragma unroll
  for (int g = 0; g < SEGN; ++g)
    zp[g*HID + h] = (y[g]-mst[g][0])*mst[g][1]*gg + bb2;
}

// ---------------------------------------------------------------- FF via MFMA bf16
#define RT 32
#define JT 256
template <int F>
__global__ __launch_bounds__(256) void k_ffmfma(float* __restrict__ x,
    const void* __restrict__ W1, long o1, const void* __restrict__ B1, long ob1,
    const void* __restrict__ W2, long o2, const void* __restrict__ B2, long ob2,
    const void* __restrict__ G, long og, const void* __restrict__ Bt, long obt,
    const int* __restrict__ flag) {
  if (*flag != F) return;
  __shared__ unsigned short hc[RT][JT + 8];   // row stride 264 us = 528 B
  __shared__ float yb[RT][66];
  int tid = threadIdx.x;
  int w = tid >> 6, lane = tid & 63;
  int col = lane & 15, quad = lane >> 4;
  int mt = w & 1, grp = w >> 1;
  long r0 = (long)blockIdx.x * RT;

  s8v a1[2];
  {
    const float* xr = x + (r0 + mt*16 + col) * HID;
#pragma unroll
    for (int ks = 0; ks < 2; ++ks) {
      const float* p = xr + ks*32 + quad*8;
      f4v u = *(const f4v*)p, v = *(const f4v*)(p + 4);
      s8v t;
      t[0]=f2b(u[0]); t[1]=f2b(u[1]); t[2]=f2b(u[2]); t[3]=f2b(u[3]);
      t[4]=f2b(v[0]); t[5]=f2b(v[1]); t[6]=f2b(v[2]); t[7]=f2b(v[3]);
      a1[ks] = t;
    }
  }

  f4v acc[2];
  acc[0] = (f4v){0.f,0.f,0.f,0.f};
  acc[1] = (f4v){0.f,0.f,0.f,0.f};

  for (int j0 = 0; j0 < FFD; j0 += JT) {
    f4v h[8];
#pragma unroll
    for (int t = 0; t < 8; ++t) h[t] = (f4v){0.f,0.f,0.f,0.f};
#pragma unroll
    for (int t = 0; t < 8; ++t) {
      long j = j0 + (grp*8 + t)*16 + col;
#pragma unroll
      for (int ks = 0; ks < 2; ++ks) {
        s8v b = ldfrag<F>(W1, o1 + j*HID + ks*32 + quad*8);
        h[t] = __builtin_amdgcn_mfma_f32_16x16x32_bf16(a1[ks], b, h[t], 0, 0, 0);
      }
    }
    __syncthreads();
#pragma unroll
    for (int t = 0; t < 8; ++t) {
      int jc = (grp*8 + t)*16 + col;
      float b1v = ldw<F>(B1, ob1 + j0 + jc);
      int row0 = mt*16 + quad*4;
#pragma unroll
      for (int r = 0; r < 4; ++r)
        hc[row0 + r][jc] = f2b(fmaxf(h[t][r] + b1v, 0.f));
    }
    __syncthreads();
#pragma unroll
    for (int kk = 0; kk < 8; ++kk) {
      s8v a = *(const s8v*)&hc[mt*16 + col][kk*32 + quad*8];
#pragma unroll
      for (int t = 0; t < 2; ++t) {
        long c = (grp*2 + t)*16 + col;
        s8v b = ldfrag<F>(W2, o2 + c*FFD + j0 + kk*32 + quad*8);
        acc[t] = __builtin_amdgcn_mfma_f32_16x16x32_bf16(a, b, acc[t], 0, 0, 0);
      }
    }
  }

#pragma unroll
  for (int t = 0; t < 2; ++t) {
    int c = (grp*2 + t)*16 + col;
    float b2v = ldw<F>(B2, ob2 + c);
    int row0 = mt*16 + quad*4;
#pragma unroll
    for (int r = 0; r < 4; ++r)
      yb[row0 + r][c] = acc[t][r] + b2v;
  }
  __syncthreads();
  float gg = ldw<F>(G, og + lane), bbt = ldw<F>(Bt, obt + lane);
#pragma unroll
  for (int rr = 0; rr < 8; ++rr) {
    int rl = w*8 + rr;
    long grow = r0 + rl;
    float val = yb[rl][lane] + x[grow*HID + lane];
    float s = val;
#pragma unroll
    for (int off = 32; off; off >>= 1) s += __shfl_xor(s, off);
    float m = s * (1.f/HID);
    float d = val - m;
    float sq = d*d;
#pragma unroll
    for (int off = 32; off; off >>= 1) sq += __shfl_xor(sq, off);
    float rv = rsqrtf(sq*(1.f/HID) + 1e-5f);
    x[grow*HID + lane] = d*rv*gg + bbt;
  }
}

// ---------------------------------------------------------------- graph qkv proj
// q,k written as bf16 (MFMA operands); v stays fp32 (transposed in k_gattn).
template <int F>
__global__ __launch_bounds__(128) void k_gqkv(const float* __restrict__ z,
    const void* __restrict__ wq, long oq, const void* __restrict__ wk, long ok,
    const void* __restrict__ wv, long ov,
    unsigned short* __restrict__ q, unsigned short* __restrict__ k,
    float* __restrict__ v, const int* __restrict__ flag) {
  if (*flag != F) return;
  __shared__ float xs[HID];
  int bg = blockIdx.x >> 10, n = blockIdx.x & 1023;
  int b = bg >> 2, g = bg & 3;
  const float* zp = z + ((long)(b*NN + n)*SEGN + g)*HID;
  int t = threadIdx.x;
  if (t < HID) xs[t] = zp[t];
  __syncthreads();
  long r = (long)bg*NN + n;
  if (t < 32) {
    long wr = oq + (long)t*HID; float a = 0;
    for (int e = 0; e < HID; ++e) a += xs[e]*ldw<F>(wq, wr + e);
    q[r*DKK + t] = f2b(a);
  } else if (t < 64) {
    long wr = ok + (long)(t-32)*HID; float a = 0;
    for (int e = 0; e < HID; ++e) a += xs[e]*ldw<F>(wk, wr + e);
    k[r*DKK + (t-32)] = f2b(a);
  } else {
    long wr = ov + (long)(t-64)*HID; float a = 0;
    for (int e = 0; e < HID; ++e) a += xs[e]*ldw<F>(wv, wr + e);
    v[r*HID + (t-64)] = a;
  }
}

// ---------------------------------------------------------------- graph attention (flash-MFMA)
// 64 queries/block (4 waves x 16), 16 chunks of 64 keys, online softmax.
// QK^T: A=Q rows bf16 (global), B=K rows bf16 (global, coalesced 1KB/wave).
// PV: A=P (LDS, stride 72), B=V^T (LDS staged+transposed, stride 72).
// Epilogue: /l, LN(att)+x in-place on z.
__global__ __launch_bounds__(256) void k_gattn(float* __restrict__ z,
    const unsigned short* __restrict__ qb, const unsigned short* __restrict__ kb,
    const float* __restrict__ vb,
    const void* __restrict__ g1, long og1, const void* __restrict__ b1, long ob1,
    const int* __restrict__ flag) {
  int f = *flag;
  __shared__ unsigned short vt[64][72];   // [vdim][key]
  __shared__ unsigned short pl[64][72];   // [q_local][key]
  __shared__ float ob[64][66];
  int tid = threadIdx.x;
  int wv = tid >> 6, lane = tid & 63;
  int col = lane & 15, quad = lane >> 4;
  int bg = blockIdx.x >> 4;
  int n0 = (blockIdx.x & 15) * 64;
  long gbase = (long)bg * NN;

  // Q A-fragment: rows n0 + wv*16 + col, k = quad*8..+7 (DKK=32 in one k-step)
  s8v aq = *(const s8v*)(qb + (gbase + n0 + wv*16 + col)*DKK + quad*8);

  f4v acc[4];
#pragma unroll
  for (int t = 0; t < 4; ++t) acc[t] = (f4v){0.f,0.f,0.f,0.f};
  float mrow[4] = {-1e30f,-1e30f,-1e30f,-1e30f};
  float lrow[4] = {0.f,0.f,0.f,0.f};
  const float rs = 0.17677669529663687f;   // 1/sqrt(32)

  // V staging coords: key pair + dim group
  int kp = (tid & 31) * 2, dg = tid >> 5;

  for (int c0 = 0; c0 < NN; c0 += 64) {
    __syncthreads();                      // prev chunk's vt/pl reads complete
    // ---- stage V chunk transposed: vt[d][key] bf16, paired b32 writes
    {
      const float* vr0 = vb + (gbase + c0 + kp)*HID + dg*8;
      const float* vr1 = vr0 + HID;
      f4v u0 = *(const f4v*)vr0, u1 = *(const f4v*)(vr0 + 4);
      f4v w0 = *(const f4v*)vr1, w1 = *(const f4v*)(vr1 + 4);
#pragma unroll
      for (int i = 0; i < 4; ++i) {
        unsigned int p0 = (unsigned int)f2b(u0[i]) | ((unsigned int)f2b(w0[i]) << 16);
        unsigned int p1 = (unsigned int)f2b(u1[i]) | ((unsigned int)f2b(w1[i]) << 16);
        *(unsigned int*)&vt[dg*8 + i][kp] = p0;
        *(unsigned int*)&vt[dg*8 + 4 + i][kp] = p1;
      }
    }
    // ---- QK^T for this wave's 16 queries x 64 keys
    f4v s[4];
#pragma unroll
    for (int nt = 0; nt < 4; ++nt) {
      s8v bk = *(const s8v*)(kb + (gbase + c0 + nt*16 + col)*DKK + quad*8);
      s[nt] = __builtin_amdgcn_mfma_f32_16x16x32_bf16(aq, bk,
                (f4v){0.f,0.f,0.f,0.f}, 0, 0, 0);
    }
    // ---- online softmax per query row (rows = quad*4+r, cols across 16 lanes)
#pragma unroll
    for (int r = 0; r < 4; ++r) {
      float s0 = s[0][r]*rs, s1 = s[1][r]*rs, s2 = s[2][r]*rs, s3 = s[3][r]*rs;
      float mc = fmaxf(fmaxf(s0, s1), fmaxf(s2, s3));
#pragma unroll
      for (int off = 1; off < 16; off <<= 1) mc = fmaxf(mc, __shfl_xor(mc, off));
      float mn = fmaxf(mrow[r], mc);
      float al = expf(mrow[r] - mn);
      mrow[r] = mn;
      float p0 = expf(s0 - mn), p1 = expf(s1 - mn), p2 = expf(s2 - mn), p3 = expf(s3 - mn);
      float su = p0 + p1 + p2 + p3;
#pragma unroll
      for (int off = 1; off < 16; off <<= 1) su += __shfl_xor(su, off);
      lrow[r] = lrow[r]*al + su;
#pragma unroll
      for (int t = 0; t < 4; ++t) acc[t][r] *= al;
      int row = wv*16 + quad*4 + r;
      pl[row][col]      = f2b(p0);
      pl[row][16 + col] = f2b(p1);
      pl[row][32 + col] = f2b(p2);
      pl[row][48 + col] = f2b(p3);
    }
    __syncthreads();                      // vt + pl visible
    // ---- PV: acc += P @ V^T
#pragma unroll
    for (int ks = 0; ks < 2; ++ks) {
      s8v ap = *(const s8v*)&pl[wv*16 + col][ks*32 + quad*8];
#pragma unroll
      for (int nt = 0; nt < 4; ++nt) {
        s8v bv = *(const s8v*)&vt[nt*16 + col][ks*32 + quad*8];
        acc[nt] = __builtin_amdgcn_mfma_f32_16x16x32_bf16(ap, bv, acc[nt], 0, 0, 0);
      }
    }
  }

  // ---- epilogue: /l -> ob, then LN + residual
  float il[4];
#pragma unroll
  for (int r = 0; r < 4; ++r) il[r] = 1.f / lrow[r];
#pragma unroll
  for (int t = 0; t < 4; ++t) {
    int row = wv*16 + quad*4;
#pragma unroll
    for (int r = 0; r < 4; ++r)
      ob[row + r][t*16 + col] = acc[t][r] * il[r];
  }
  __syncthreads();
  int b = bg >> 2, g = bg & 3;
  float gg = f ? ((const float*)g1)[og1 + lane] : b2f(((const bf16*)g1)[og1 + lane]);
  float bb = f ? ((const float*)b1)[ob1 + lane] : b2f(((const bf16*)b1)[ob1 + lane]);
#pragma unroll
  for (int rr = 0; rr < 16; ++rr) {
    int rl = wv*16 + rr;
    int n = n0 + rl;
    float val = ob[rl][lane];
    float s = val;
#pragma unroll
    for (int off = 32; off; off >>= 1) s += __shfl_xor(s, off);
    float m = s*(1.f/HID);
    float d = val - m, sq = d*d;
#pragma unroll
    for (int off = 32; off; off >>= 1) sq += __shfl_xor(sq, off);
    float r = rsqrtf(sq*(1.f/HID) + 1e-5f);
    float* zp = z + ((long)(b*NN + n)*SEGN + g)*HID;
    zp[lane] = d*r*gg + bb + zp[lane];   // LN(att) + x
  }
}

// ---------------------------------------------------------------- pool over segments
__global__ __launch_bounds__(64) void k_pool(const float* __restrict__ z,
    float* __restrict__ enc, int s) {
  int b = blockIdx.x >> 10, n = blockIdx.x & 1023, h = threadIdx.x;
  const float* zp = z + (long)(b*NN + n)*SEGN*HID;
  float a = 0;
#pragma unroll
  for (int g = 0; g < SEGN; ++g) a += zp[g*HID + h];
  enc[(long)(b*NN + n)*(2*HID) + s*HID + h] = a*0.25f;
}

// ---------------------------------------------------------------- final qkv proj (in_dim=128)
template <int F>
__global__ __launch_bounds__(128) void k_fqkv(const float* __restrict__ enc,
    const void* __restrict__ wq, const void* __restrict__ wk,
    const void* __restrict__ wv,
    float* __restrict__ q, float* __restrict__ k, float* __restrict__ v,
    const int* __restrict__ flag) {
  if (*flag != F) return;
  __shared__ float xs[2*HID];
  long r = blockIdx.x;
  int t = threadIdx.x;
  xs[t] = enc[r*128 + t];
  __syncthreads();
  if (t < 32) {
    long wr = (long)t*128; float a = 0;
    for (int e = 0; e < 128; ++e) a += xs[e]*ldw<F>(wq, wr + e);
    q[r*DKK + t] = a;
  } else if (t < 64) {
    long wr = (long)(t-32)*128; float a = 0;
    for (int e = 0; e < 128; ++e) a += xs[e]*ldw<F>(wk, wr + e);
    k[r*DKK + (t-32)] = a;
  } else {
    long wr = (long)(t-64)*128; float a = 0;
    for (int e = 0; e < 128; ++e) a += xs[e]*ldw<F>(wv, wr + e);
    v[r*HID + (t-64)] = a;
  }
}

// ---------------------------------------------------------------- final attention -> d_out
#define QB 8
#define TM 64
__global__ __launch_bounds__(256) void k_fattn(const float* __restrict__ q,
    const float* __restrict__ k, const float* __restrict__ v,
    void* __restrict__ outp, const int* __restrict__ flag) {
  __shared__ float qs[QB][DKK];
  __shared__ float sc[QB][NN];
  __shared__ float tile[TM*66];
  __shared__ float oacc[QB][HID];
  int tid = threadIdx.x;
  int wave = tid >> 6, lane = tid & 63;
  int b = blockIdx.x >> 7;
  int n0 = (blockIdx.x & 127) * QB;
  if (tid < QB*DKK)
    qs[tid >> 5][tid & 31] = q[((long)b*NN + n0 + (tid >> 5))*DKK + (tid & 31)];
  __syncthreads();
  const float rs = 0.17677669529663687f;
  for (int m0 = 0; m0 < NN; m0 += TM) {
    for (int i = tid; i < TM*DKK; i += 256)
      tile[(i >> 5)*33 + (i & 31)] = k[((long)b*NN + m0)*DKK + i];
    __syncthreads();
    for (int tt = tid; tt < QB*TM; tt += 256) {
      int qq = tt >> 6, mm = tt & 63;
      const float* kt = &tile[mm*33];
      const float* qp = qs[qq];
      float a = 0;
#pragma unroll
      for (int e = 0; e < DKK; ++e) a += qp[e]*kt[e];
      sc[qq][m0 + mm] = a*rs;
    }
    __syncthreads();
  }
  for (int qq = wave*2; qq < wave*2 + 2; ++qq) {
    float mx = -1e30f;
    for (int mm = lane; mm < NN; mm += 64) mx = fmaxf(mx, sc[qq][mm]);
#pragma unroll
    for (int off = 32; off; off >>= 1) mx = fmaxf(mx, __shfl_xor(mx, off));
    float se = 0;
    for (int mm = lane; mm < NN; mm += 64) { float e = expf(sc[qq][mm]-mx); sc[qq][mm] = e; se += e; }
#pragma unroll
    for (int off = 32; off; off >>= 1) se += __shfl_xor(se, off);
    float inv = 1.f/se;
    for (int mm = lane; mm < NN; mm += 64) sc[qq][mm] *= inv;
  }
  for (int i = tid; i < QB*HID; i += 256) oacc[i >> 6][i & 63] = 0.f;
  __syncthreads();
  for (int m0 = 0; m0 < NN; m0 += TM) {
    for (int i = tid; i < TM*HID; i += 256)
      tile[i] = v[((long)b*NN + m0)*HID + i];
    __syncthreads();
    for (int tt = tid; tt < QB*HID; tt += 256) {
      int qq = tt >> 6, hh = tt & 63;
      float a = oacc[qq][hh];
      const float* sp = &sc[qq][m0];
      for (int mm = 0; mm < TM; ++mm) a += sp[mm]*tile[mm*HID + hh];
      oacc[qq][hh] = a;
    }
    __syncthreads();
  }
  int f = *flag;
  for (int qq = wave*2; qq < wave*2 + 2; ++qq) {
    float val = oacc[qq][lane];
    long idx = ((long)(b*NN + n0 + qq))*HID + lane;
    if (f) ((float*)outp)[idx] = val;
    else   ((bf16*)outp)[idx] = __float2bfloat16(val);
  }
}

// ================================================================ launch
extern "C" void kernel_launch(void* const* d_in, const int* in_sizes, int n_in,
                              void* d_out, int out_size, void* d_ws, size_t ws_size,
                              hipStream_t stream) {
  static const int EXP[30] = {
    49152, 49152, 384, 128, 49152, 768, 16384, 256,
    524288, 8192, 524288, 256, 256, 256, 256, 256,
    8192, 8192, 16384, 524288, 8192, 524288, 256, 256,
    256, 256, 256, 4096, 4096, 8192
  };
  const size_t NEED = (size_t)(1048576 + 524288 + 524288 + 524288 + 1048576) * 4 + 64;
  bool ok = (n_in == 30) && (ws_size >= NEED) && (out_size == BB*NN*HID);
  if (ok) for (int i = 0; i < 30; ++i) ok = ok && (in_sizes[i] == EXP[i]);
  if (!ok) {
    k_zero<<<(BB*NN*HID + 255)/256, 256, 0, stream>>>((unsigned short*)d_out, BB*NN*HID);
    return;
  }

  float* z   = (float*)d_ws;             // [4,1024,4,64]
  float* enc = z   + 1048576;            // [4,1024,128]
  float* qb  = enc + 524288;             // [16,1024,32] (bf16 for gattn, fp32 for fattn)
  float* kb  = qb  + 524288;
  float* vb  = kb  + 524288;             // [16,1024,64] fp32
  int*  flag = (int*)(vb + 1048576);

  k_detect<<<1, 256, 0, stream>>>(d_in[0], flag);

  const void *i_traffic=d_in[0], *i_user=d_in[1], *i_pw=d_in[2], *i_pb=d_in[3],
    *i_mw=d_in[4], *i_mb=d_in[5], *i_ow=d_in[6], *i_ob=d_in[7], *i_f1w=d_in[8],
    *i_f1b=d_in[9], *i_f2w=d_in[10], *i_f2b=d_in[11], *i_l1g=d_in[12],
    *i_l1b=d_in[13], *i_l2g=d_in[14], *i_l2b=d_in[15], *i_gwq=d_in[16],
    *i_gwk=d_in[17], *i_gwv=d_in[18], *i_gf1w=d_in[19], *i_gf1b=d_in[20],
    *i_gf2w=d_in[21], *i_gf2b=d_in[22], *i_gl1g=d_in[23], *i_gl1b=d_in[24],
    *i_gl2g=d_in[25], *i_gl2b=d_in[26], *i_cwq=d_in[27], *i_cwk=d_in[28],
    *i_cwv=d_in[29];

  const int FFG = BB*NN*SEGN/RT;         // 512 blocks

  for (int s = 0; s < 2; ++s) {
    const void* x = s ? i_user : i_traffic;
    k_patch<0><<<BB*NN, 256, 0, stream>>>(x, i_pw, (long)s*HID*SEGL, i_pb, (long)s*HID, z, flag);
    k_patch<1><<<BB*NN, 256, 0, stream>>>(x, i_pw, (long)s*HID*SEGL, i_pb, (long)s*HID, z, flag);
    for (int i = 0; i < 2; ++i) {
      long si = s*2 + i;
      k_tattn<0><<<BB*NN, 64, 0, stream>>>(z,
          i_mw, si*3*HID*HID, i_mb, si*3*HID, i_ow, si*HID*HID, i_ob, si*HID,
          i_l1g, si*HID, i_l1b, si*HID, flag);
      k_tattn<1><<<BB*NN, 64, 0, stream>>>(z,
          i_mw, si*3*HID*HID, i_mb, si*3*HID, i_ow, si*HID*HID, i_ob, si*HID,
          i_l1g, si*HID, i_l1b, si*HID, flag);
      k_ffmfma<0><<<FFG, 256, 0, stream>>>(z,
          i_f1w, si*FFD*HID, i_f1b, si*FFD, i_f2w, si*HID*FFD, i_f2b, si*HID,
          i_l2g, si*HID, i_l2b, si*HID, flag);
      k_ffmfma<1><<<FFG, 256, 0, stream>>>(z,
          i_f1w, si*FFD*HID, i_f1b, si*FFD, i_f2w, si*HID*FFD, i_f2b, si*HID,
          i_l2g, si*HID, i_l2b, si*HID, flag);
      k_gqkv<0><<<16*NN, 128, 0, stream>>>(z,
          i_gwq, si*DKK*HID, i_gwk, si*DKK*HID, i_gwv, si*HID*HID,
          (unsigned short*)qb, (unsigned short*)kb, vb, flag);
      k_gqkv<1><<<16*NN, 128, 0, stream>>>(z,
          i_gwq, si*DKK*HID, i_gwk, si*DKK*HID, i_gwv, si*HID*HID,
          (unsigned short*)qb, (unsigned short*)kb, vb, flag);
      k_gattn<<<16*16, 256, 0, stream>>>(z,
          (const unsigned short*)qb, (const unsigned short*)kb, vb,
          i_gl1g, si*HID, i_gl1b, si*HID, flag);
      k_ffmfma<0><<<FFG, 256, 0, stream>>>(z,
          i_gf1w, si*FFD*HID, i_gf1b, si*FFD, i_gf2w, si*HID*FFD, i_gf2b, si*HID,
          i_gl2g, si*HID, i_gl2b, si*HID, flag);
      k_ffmfma<1><<<FFG, 256, 0, stream>>>(z,
          i_gf1w, si*FFD*HID, i_gf1b, si*FFD, i_gf2w, si*HID*FFD, i_gf2b, si*HID,
          i_gl2g, si*HID, i_gl2b, si*HID, flag);
    }
    k_pool<<<BB*NN, 64, 0, stream>>>(z, enc, s);
  }
  k_fqkv<0><<<BB*NN, 128, 0, stream>>>(enc, i_cwq, i_cwk, i_cwv, qb, kb, vb, flag);
  k_fqkv<1><<<BB*NN, 128, 0, stream>>>(enc, i_cwq, i_cwk, i_cwv, qb, kb, vb, flag);
  k_fattn<<<BB*(NN/QB), 256, 0, stream>>>(qb, kb, vb, d_out, flag);
}

// Round 6
// 1977.158 us; speedup vs baseline: 3.8526x; 1.0375x over previous
//
#include <hip/hip_runtime.h>
#include <hip/hip_bf16.h>
#include <math.h>

// Problem constants
#define BB 4
#define SEQL 12
#define NN 1024
#define SEGL 3
#define SEGN 4
#define HID 64
#define FFD 2048
#define DKK 32
#define NHH 8
#define HDD 8

using bf16 = __hip_bfloat16;
__device__ __forceinline__ float b2f(bf16 v) { return __bfloat162float(v); }

typedef __attribute__((ext_vector_type(8))) short s8v;   // 8 bf16 (4 VGPRs)
typedef __attribute__((ext_vector_type(4))) float f4v;   // MFMA C/D

__device__ __forceinline__ unsigned short f2b(float f) {
  bf16 h = __float2bfloat16(f);
  unsigned short u; __builtin_memcpy(&u, &h, 2); return u;
}

// dtype-templated weight load: F=1 fp32 storage, F=0 bf16 storage
template <int F>
__device__ __forceinline__ float ldw(const void* p, long i) {
  if (F) return ((const float*)p)[i];
  return b2f(((const bf16*)p)[i]);
}

// 8-element bf16 fragment load from weight array at element offset (multiple of 8)
template <int F>
__device__ __forceinline__ s8v ldfrag(const void* p, long elemOff) {
  if (F) {
    const float* fp = (const float*)p + elemOff;
    f4v u = *(const f4v*)fp, v = *(const f4v*)(fp + 4);
    s8v t;
    t[0]=f2b(u[0]); t[1]=f2b(u[1]); t[2]=f2b(u[2]); t[3]=f2b(u[3]);
    t[4]=f2b(v[0]); t[5]=f2b(v[1]); t[6]=f2b(v[2]); t[7]=f2b(v[3]);
    return t;
  }
  return *(const s8v*)((const unsigned short*)p + elemOff);
}

// ---------------------------------------------------------------- zero-fill d_out (guard path)
__global__ void k_zero(unsigned short* __restrict__ o, int n) {
  int i = blockIdx.x * 256 + threadIdx.x;
  if (i < n) o[i] = 0;
}

// ---------------------------------------------------------------- detect dtype
__global__ void k_detect(const void* __restrict__ x0, int* __restrict__ flag) {
  int t = threadIdx.x;
  int bad = 0;
  const bf16* p = (const bf16*)x0;
  for (int i = t; i < 512; i += 256) {
    float a = fabsf(b2f(p[i]));
    if (!(a < 1e4f) || (a != 0.f && a < 1e-4f)) bad = 1;
  }
  __shared__ int tot;
  if (t == 0) tot = 0;
  __syncthreads();
  unsigned long long m = __ballot(bad);
  if ((t & 63) == 0) atomicAdd(&tot, __popcll(m));
  __syncthreads();
  if (t == 0) *flag = (tot > 64) ? 1 : 0;   // 1 = fp32 storage, 0 = bf16
}

// ---------------------------------------------------------------- patch embed
template <int F>
__global__ __launch_bounds__(256) void k_patch(const void* __restrict__ x,
    const void* __restrict__ pw, long opw, const void* __restrict__ pb, long opb,
    float* __restrict__ z, const int* __restrict__ flag) {
  if (*flag != F) return;
  int b = blockIdx.x >> 10, n = blockIdx.x & 1023;
  int g = threadIdx.x >> 6, h = threadIdx.x & 63;
  float acc = ldw<F>(pb, opb + h);
#pragma unroll
  for (int l = 0; l < SEGL; ++l)
    acc += ldw<F>(x, (long)(b*SEQL + g*SEGL + l)*NN + n) * ldw<F>(pw, opw + h*SEGL + l);
  int i2 = h >> 1;
  float dv = expf((float)(2*i2) * (-logf(10000.f) / (float)HID));
  float ang = (float)g * dv;
  acc += (h & 1) ? cosf(ang) : sinf(ang);
  z[((long)(b*NN + n)*SEGN + g)*HID + h] = acc;
}

// ---------------------------------------------------------------- temporal MHA + LN1
template <int F>
__global__ __launch_bounds__(64) void k_tattn(float* __restrict__ z,
    const void* __restrict__ W, long oW, const void* __restrict__ bqkv, long obq,
    const void* __restrict__ WO, long oWO, const void* __restrict__ bo, long obo,
    const void* __restrict__ g1, long og1, const void* __restrict__ b1, long ob1,
    const int* __restrict__ flag) {
  if (*flag != F) return;
  __shared__ float xr[SEGN][HID];
  __shared__ float qkv[SEGN][3*HID];
  __shared__ float ao[SEGN][HID];
  __shared__ float mst[SEGN][2];
  int h = threadIdx.x;
  float* zp = z + (long)blockIdx.x * SEGN * HID;
#pragma unroll
  for (int g = 0; g < SEGN; ++g) xr[g][h] = zp[g*HID + h];
  __syncthreads();
#pragma unroll
  for (int j = 0; j < 3; ++j) {
    int c = j*HID + h;
    long wr = oW + (long)c*HID;
    float a0=0,a1=0,a2=0,a3=0;
    for (int k = 0; k < HID; ++k) {
      float w = ldw<F>(W, wr + k);
      a0 += xr[0][k]*w; a1 += xr[1][k]*w; a2 += xr[2][k]*w; a3 += xr[3][k]*w;
    }
    float bb = ldw<F>(bqkv, obq + c);
    qkv[0][c]=a0+bb; qkv[1][c]=a1+bb; qkv[2][c]=a2+bb; qkv[3][c]=a3+bb;
  }
  __syncthreads();
  if (h < NHH*SEGN) {
    int head = h >> 2, qt = h & 3;
    const float scale = 0.3535533905932738f;   // 1/sqrt(8)
    float s[SEGN]; float mx = -1e30f;
#pragma unroll
    for (int kt = 0; kt < SEGN; ++kt) {
      float d = 0;
#pragma unroll
      for (int e = 0; e < HDD; ++e) d += qkv[qt][head*HDD+e]*qkv[kt][HID+head*HDD+e];
      s[kt] = d*scale; mx = fmaxf(mx, s[kt]);
    }
    float se = 0;
#pragma unroll
    for (int kt = 0; kt < SEGN; ++kt) { s[kt] = expf(s[kt]-mx); se += s[kt]; }
    float inv = 1.f/se;
#pragma unroll
    for (int e = 0; e < HDD; ++e) {
      float o = 0;
#pragma unroll
      for (int kt = 0; kt < SEGN; ++kt) o += s[kt]*qkv[kt][2*HID+head*HDD+e];
      ao[qt][head*HDD+e] = o*inv;
    }
  }
  __syncthreads();
  float y[SEGN];
  {
    long wr = oWO + (long)h*HID;
    float bb = ldw<F>(bo, obo + h);
#pragma unroll
    for (int g = 0; g < SEGN; ++g) {
      float a = bb;
      for (int k = 0; k < HID; ++k) a += ao[g][k]*ldw<F>(WO, wr + k);
      y[g] = xr[g][h] + a;    // residual
    }
  }
  __syncthreads();
#pragma unroll
  for (int g = 0; g < SEGN; ++g) xr[g][h] = y[g];
  __syncthreads();
  if (h < SEGN) {
    float m = 0;
    for (int k = 0; k < HID; ++k) m += xr[h][k];
    m *= (1.f/HID);
    float v = 0;
    for (int k = 0; k < HID; ++k) { float d = xr[h][k]-m; v += d*d; }
    mst[h][0] = m; mst[h][1] = rsqrtf(v*(1.f/HID) + 1e-5f);
  }
  __syncthreads();
  float gg = ldw<F>(g1, og1 + h), bb2 = ldw<F>(b1, ob1 + h);
#pragma unroll
  for (int g = 0; g < SEGN; ++g)
    zp[g*HID + h] = (y[g]-mst[g][0])*mst[g][1]*gg + bb2;
}

// ---------------------------------------------------------------- FF via MFMA bf16 (v2)
// 16 rows/block -> 1024 blocks (4/CU). Both GEMMs operand-swapped so the
// C/D layout packs: GEMM1 spill = one b64/tile (vs 4x b16), epilogue = f4v.
// hcT[xrow][hidden-chunk] stride 264us = 528B (16B aligned reads).
#define FRW 16
#define JT 256
template <int F>
__global__ __launch_bounds__(256) void k_ffmfma(float* __restrict__ x,
    const void* __restrict__ W1, long o1, const void* __restrict__ B1, long ob1,
    const void* __restrict__ W2, long o2, const void* __restrict__ B2, long ob2,
    const void* __restrict__ G, long og, const void* __restrict__ Bt, long obt,
    const int* __restrict__ flag) {
  if (*flag != F) return;
  __shared__ unsigned short hcT[FRW][JT + 8];
  __shared__ float yb[FRW][68];
  int tid = threadIdx.x;
  int w = tid >> 6, lane = tid & 63;
  int col = lane & 15, quad = lane >> 4;
  long r0 = (long)blockIdx.x * FRW;

  // X B-fragments (n = xrow = col, k = ks*32 + quad*8), constant across chunks
  s8v bx[2];
  {
    const float* xr = x + (r0 + col) * HID;
#pragma unroll
    for (int ks = 0; ks < 2; ++ks) {
      const float* p = xr + ks*32 + quad*8;
      f4v u = *(const f4v*)p, v = *(const f4v*)(p + 4);
      s8v t;
      t[0]=f2b(u[0]); t[1]=f2b(u[1]); t[2]=f2b(u[2]); t[3]=f2b(u[3]);
      t[4]=f2b(v[0]); t[5]=f2b(v[1]); t[6]=f2b(v[2]); t[7]=f2b(v[3]);
      bx[ks] = t;
    }
  }

  f4v acc = (f4v){0.f,0.f,0.f,0.f};      // Y^T: out rows (w*16+quad*4+r), xrow col

  for (int j0 = 0; j0 < FFD; j0 += JT) {
    // ---- GEMM1 (S^T = W1c @ X^T): wave covers hidden tiles (w*4+t)*16
    f4v s[4];
#pragma unroll
    for (int t = 0; t < 4; ++t) {
      int ht = (w*4 + t) * 16;
      long j = j0 + ht + col;            // A m-row = W1 row (hidden idx)
      f4v sv = (f4v){0.f,0.f,0.f,0.f};
#pragma unroll
      for (int ks = 0; ks < 2; ++ks) {
        s8v aw = ldfrag<F>(W1, o1 + j*HID + ks*32 + quad*8);
        sv = __builtin_amdgcn_mfma_f32_16x16x32_bf16(aw, bx[ks], sv, 0, 0, 0);
      }
      s[t] = sv;
    }
    __syncthreads();                     // prev chunk's GEMM2 reads done
#pragma unroll
    for (int t = 0; t < 4; ++t) {
      int hl = (w*4 + t) * 16 + quad*4;  // hidden-local of regs 0..3
      unsigned short pk[4];
#pragma unroll
      for (int r = 0; r < 4; ++r) {
        float b1v = ldw<F>(B1, ob1 + j0 + hl + r);
        pk[r] = f2b(fmaxf(s[t][r] + b1v, 0.f));
      }
      *(unsigned long long*)&hcT[col][hl] =
        (unsigned long long)pk[0] | ((unsigned long long)pk[1] << 16) |
        ((unsigned long long)pk[2] << 32) | ((unsigned long long)pk[3] << 48);
    }
    __syncthreads();
    // ---- GEMM2 (Y^T += W2c @ Hc^T): wave's out tile = w*16
#pragma unroll
    for (int ks = 0; ks < 8; ++ks) {
      s8v aw = ldfrag<F>(W2, o2 + (long)(w*16 + col)*FFD + j0 + ks*32 + quad*8);
      s8v bh = *(const s8v*)&hcT[col][ks*32 + quad*8];
      acc = __builtin_amdgcn_mfma_f32_16x16x32_bf16(aw, bh, acc, 0, 0, 0);
    }
  }

  // ---- epilogue: +B2 -> yb (f4v packed), then residual + LN
  {
    int ol = w*16 + quad*4;
    f4v yv;
#pragma unroll
    for (int r = 0; r < 4; ++r) yv[r] = acc[r] + ldw<F>(B2, ob2 + ol + r);
    *(f4v*)&yb[col][ol] = yv;
  }
  __syncthreads();
  float gg = ldw<F>(G, og + lane), bbt = ldw<F>(Bt, obt + lane);
#pragma unroll
  for (int rr = 0; rr < 4; ++rr) {
    int rl = w*4 + rr;
    long grow = r0 + rl;
    float val = yb[rl][lane] + x[grow*HID + lane];
    float s = val;
#pragma unroll
    for (int off = 32; off; off >>= 1) s += __shfl_xor(s, off);
    float m = s * (1.f/HID);
    float d = val - m;
    float sq = d*d;
#pragma unroll
    for (int off = 32; off; off >>= 1) sq += __shfl_xor(sq, off);
    float rv = rsqrtf(sq*(1.f/HID) + 1e-5f);
    x[grow*HID + lane] = d*rv*gg + bbt;
  }
}

// ---------------------------------------------------------------- graph qkv proj
// q,k written as bf16 (MFMA operands); v stays fp32 (transposed in k_gattn).
template <int F>
__global__ __launch_bounds__(128) void k_gqkv(const float* __restrict__ z,
    const void* __restrict__ wq, long oq, const void* __restrict__ wk, long ok,
    const void* __restrict__ wv, long ov,
    unsigned short* __restrict__ q, unsigned short* __restrict__ k,
    float* __restrict__ v, const int* __restrict__ flag) {
  if (*flag != F) return;
  __shared__ float xs[HID];
  int bg = blockIdx.x >> 10, n = blockIdx.x & 1023;
  int b = bg >> 2, g = bg & 3;
  const float* zp = z + ((long)(b*NN + n)*SEGN + g)*HID;
  int t = threadIdx.x;
  if (t < HID) xs[t] = zp[t];
  __syncthreads();
  long r = (long)bg*NN + n;
  if (t < 32) {
    long wr = oq + (long)t*HID; float a = 0;
    for (int e = 0; e < HID; ++e) a += xs[e]*ldw<F>(wq, wr + e);
    q[r*DKK + t] = f2b(a);
  } else if (t < 64) {
    long wr = ok + (long)(t-32)*HID; float a = 0;
    for (int e = 0; e < HID; ++e) a += xs[e]*ldw<F>(wk, wr + e);
    k[r*DKK + (t-32)] = f2b(a);
  } else {
    long wr = ov + (long)(t-64)*HID; float a = 0;
    for (int e = 0; e < HID; ++e) a += xs[e]*ldw<F>(wv, wr + e);
    v[r*HID + (t-64)] = a;
  }
}

// ---------------------------------------------------------------- graph attention (flash-MFMA)
__global__ __launch_bounds__(256) void k_gattn(float* __restrict__ z,
    const unsigned short* __restrict__ qb, const unsigned short* __restrict__ kb,
    const float* __restrict__ vb,
    const void* __restrict__ g1, long og1, const void* __restrict__ b1, long ob1,
    const int* __restrict__ flag) {
  int f = *flag;
  __shared__ unsigned short vt[64][72];   // [vdim][key]
  __shared__ unsigned short pl[64][72];   // [q_local][key]
  __shared__ float ob[64][66];
  int tid = threadIdx.x;
  int wv = tid >> 6, lane = tid & 63;
  int col = lane & 15, quad = lane >> 4;
  int bg = blockIdx.x >> 4;
  int n0 = (blockIdx.x & 15) * 64;
  long gbase = (long)bg * NN;

  s8v aq = *(const s8v*)(qb + (gbase + n0 + wv*16 + col)*DKK + quad*8);

  f4v acc[4];
#pragma unroll
  for (int t = 0; t < 4; ++t) acc[t] = (f4v){0.f,0.f,0.f,0.f};
  float mrow[4] = {-1e30f,-1e30f,-1e30f,-1e30f};
  float lrow[4] = {0.f,0.f,0.f,0.f};
  const float rs = 0.17677669529663687f;   // 1/sqrt(32)

  int kp = (tid & 31) * 2, dg = tid >> 5;

  for (int c0 = 0; c0 < NN; c0 += 64) {
    __syncthreads();
    {
      const float* vr0 = vb + (gbase + c0 + kp)*HID + dg*8;
      const float* vr1 = vr0 + HID;
      f4v u0 = *(const f4v*)vr0, u1 = *(const f4v*)(vr0 + 4);
      f4v w0 = *(const f4v*)vr1, w1 = *(const f4v*)(vr1 + 4);
#pragma unroll
      for (int i = 0; i < 4; ++i) {
        unsigned int p0 = (unsigned int)f2b(u0[i]) | ((unsigned int)f2b(w0[i]) << 16);
        unsigned int p1 = (unsigned int)f2b(u1[i]) | ((unsigned int)f2b(w1[i]) << 16);
        *(unsigned int*)&vt[dg*8 + i][kp] = p0;
        *(unsigned int*)&vt[dg*8 + 4 + i][kp] = p1;
      }
    }
    f4v s[4];
#pragma unroll
    for (int nt = 0; nt < 4; ++nt) {
      s8v bk = *(const s8v*)(kb + (gbase + c0 + nt*16 + col)*DKK + quad*8);
      s[nt] = __builtin_amdgcn_mfma_f32_16x16x32_bf16(aq, bk,
                (f4v){0.f,0.f,0.f,0.f}, 0, 0, 0);
    }
#pragma unroll
    for (int r = 0; r < 4; ++r) {
      float s0 = s[0][r]*rs, s1 = s[1][r]*rs, s2 = s[2][r]*rs, s3 = s[3][r]*rs;
      float mc = fmaxf(fmaxf(s0, s1), fmaxf(s2, s3));
#pragma unroll
      for (int off = 1; off < 16; off <<= 1) mc = fmaxf(mc, __shfl_xor(mc, off));
      float mn = fmaxf(mrow[r], mc);
      float al = expf(mrow[r] - mn);
      mrow[r] = mn;
      float p0 = expf(s0 - mn), p1 = expf(s1 - mn), p2 = expf(s2 - mn), p3 = expf(s3 - mn);
      float su = p0 + p1 + p2 + p3;
#pragma unroll
      for (int off = 1; off < 16; off <<= 1) su += __shfl_xor(su, off);
      lrow[r] = lrow[r]*al + su;
#pragma unroll
      for (int t = 0; t < 4; ++t) acc[t][r] *= al;
      int row = wv*16 + quad*4 + r;
      pl[row][col]      = f2b(p0);
      pl[row][16 + col] = f2b(p1);
      pl[row][32 + col] = f2b(p2);
      pl[row][48 + col] = f2b(p3);
    }
    __syncthreads();
#pragma unroll
    for (int ks = 0; ks < 2; ++ks) {
      s8v ap = *(const s8v*)&pl[wv*16 + col][ks*32 + quad*8];
#pragma unroll
      for (int nt = 0; nt < 4; ++nt) {
        s8v bv = *(const s8v*)&vt[nt*16 + col][ks*32 + quad*8];
        acc[nt] = __builtin_amdgcn_mfma_f32_16x16x32_bf16(ap, bv, acc[nt], 0, 0, 0);
      }
    }
  }

  float il[4];
#pragma unroll
  for (int r = 0; r < 4; ++r) il[r] = 1.f / lrow[r];
#pragma unroll
  for (int t = 0; t < 4; ++t) {
    int row = wv*16 + quad*4;
#pragma unroll
    for (int r = 0; r < 4; ++r)
      ob[row + r][t*16 + col] = acc[t][r] * il[r];
  }
  __syncthreads();
  int b = bg >> 2, g = bg & 3;
  float gg = f ? ((const float*)g1)[og1 + lane] : b2f(((const bf16*)g1)[og1 + lane]);
  float bb = f ? ((const float*)b1)[ob1 + lane] : b2f(((const bf16*)b1)[ob1 + lane]);
#pragma unroll
  for (int rr = 0; rr < 16; ++rr) {
    int rl = wv*16 + rr;
    int n = n0 + rl;
    float val = ob[rl][lane];
    float s = val;
#pragma unroll
    for (int off = 32; off; off >>= 1) s += __shfl_xor(s, off);
    float m = s*(1.f/HID);
    float d = val - m, sq = d*d;
#pragma unroll
    for (int off = 32; off; off >>= 1) sq += __shfl_xor(sq, off);
    float r = rsqrtf(sq*(1.f/HID) + 1e-5f);
    float* zp = z + ((long)(b*NN + n)*SEGN + g)*HID;
    zp[lane] = d*r*gg + bb + zp[lane];   // LN(att) + x
  }
}

// ---------------------------------------------------------------- pool over segments
__global__ __launch_bounds__(64) void k_pool(const float* __restrict__ z,
    float* __restrict__ enc, int s) {
  int b = blockIdx.x >> 10, n = blockIdx.x & 1023, h = threadIdx.x;
  const float* zp = z + (long)(b*NN + n)*SEGN*HID;
  float a = 0;
#pragma unroll
  for (int g = 0; g < SEGN; ++g) a += zp[g*HID + h];
  enc[(long)(b*NN + n)*(2*HID) + s*HID + h] = a*0.25f;
}

// ---------------------------------------------------------------- final qkv proj (in_dim=128)
template <int F>
__global__ __launch_bounds__(128) void k_fqkv(const float* __restrict__ enc,
    const void* __restrict__ wq, const void* __restrict__ wk,
    const void* __restrict__ wv,
    float* __restrict__ q, float* __restrict__ k, float* __restrict__ v,
    const int* __restrict__ flag) {
  if (*flag != F) return;
  __shared__ float xs[2*HID];
  long r = blockIdx.x;
  int t = threadIdx.x;
  xs[t] = enc[r*128 + t];
  __syncthreads();
  if (t < 32) {
    long wr = (long)t*128; float a = 0;
    for (int e = 0; e < 128; ++e) a += xs[e]*ldw<F>(wq, wr + e);
    q[r*DKK + t] = a;
  } else if (t < 64) {
    long wr = (long)(t-32)*128; float a = 0;
    for (int e = 0; e < 128; ++e) a += xs[e]*ldw<F>(wk, wr + e);
    k[r*DKK + (t-32)] = a;
  } else {
    long wr = (long)(t-64)*128; float a = 0;
    for (int e = 0; e < 128; ++e) a += xs[e]*ldw<F>(wv, wr + e);
    v[r*HID + (t-64)] = a;
  }
}

// ---------------------------------------------------------------- final attention -> d_out
#define QB 8
#define TM 64
__global__ __launch_bounds__(256) void k_fattn(const float* __restrict__ q,
    const float* __restrict__ k, const float* __restrict__ v,
    void* __restrict__ outp, const int* __restrict__ flag) {
  __shared__ float qs[QB][DKK];
  __shared__ float sc[QB][NN];
  __shared__ float tile[TM*66];
  __shared__ float oacc[QB][HID];
  int tid = threadIdx.x;
  int wave = tid >> 6, lane = tid & 63;
  int b = blockIdx.x >> 7;
  int n0 = (blockIdx.x & 127) * QB;
  if (tid < QB*DKK)
    qs[tid >> 5][tid & 31] = q[((long)b*NN + n0 + (tid >> 5))*DKK + (tid & 31)];
  __syncthreads();
  const float rs = 0.17677669529663687f;
  for (int m0 = 0; m0 < NN; m0 += TM) {
    for (int i = tid; i < TM*DKK; i += 256)
      tile[(i >> 5)*33 + (i & 31)] = k[((long)b*NN + m0)*DKK + i];
    __syncthreads();
    for (int tt = tid; tt < QB*TM; tt += 256) {
      int qq = tt >> 6, mm = tt & 63;
      const float* kt = &tile[mm*33];
      const float* qp = qs[qq];
      float a = 0;
#pragma unroll
      for (int e = 0; e < DKK; ++e) a += qp[e]*kt[e];
      sc[qq][m0 + mm] = a*rs;
    }
    __syncthreads();
  }
  for (int qq = wave*2; qq < wave*2 + 2; ++qq) {
    float mx = -1e30f;
    for (int mm = lane; mm < NN; mm += 64) mx = fmaxf(mx, sc[qq][mm]);
#pragma unroll
    for (int off = 32; off; off >>= 1) mx = fmaxf(mx, __shfl_xor(mx, off));
    float se = 0;
    for (int mm = lane; mm < NN; mm += 64) { float e = expf(sc[qq][mm]-mx); sc[qq][mm] = e; se += e; }
#pragma unroll
    for (int off = 32; off; off >>= 1) se += __shfl_xor(se, off);
    float inv = 1.f/se;
    for (int mm = lane; mm < NN; mm += 64) sc[qq][mm] *= inv;
  }
  for (int i = tid; i < QB*HID; i += 256) oacc[i >> 6][i & 63] = 0.f;
  __syncthreads();
  for (int m0 = 0; m0 < NN; m0 += TM) {
    for (int i = tid; i < TM*HID; i += 256)
      tile[i] = v[((long)b*NN + m0)*HID + i];
    __syncthreads();
    for (int tt = tid; tt < QB*HID; tt += 256) {
      int qq = tt >> 6, hh = tt & 63;
      float a = oacc[qq][hh];
      const float* sp = &sc[qq][m0];
      for (int mm = 0; mm < TM; ++mm) a += sp[mm]*tile[mm*HID + hh];
      oacc[qq][hh] = a;
    }
    __syncthreads();
  }
  int f = *flag;
  for (int qq = wave*2; qq < wave*2 + 2; ++qq) {
    float val = oacc[qq][lane];
    long idx = ((long)(b*NN + n0 + qq))*HID + lane;
    if (f) ((float*)outp)[idx] = val;
    else   ((bf16*)outp)[idx] = __float2bfloat16(val);
  }
}

// ================================================================ launch
extern "C" void kernel_launch(void* const* d_in, const int* in_sizes, int n_in,
                              void* d_out, int out_size, void* d_ws, size_t ws_size,
                              hipStream_t stream) {
  static const int EXP[30] = {
    49152, 49152, 384, 128, 49152, 768, 16384, 256,
    524288, 8192, 524288, 256, 256, 256, 256, 256,
    8192, 8192, 16384, 524288, 8192, 524288, 256, 256,
    256, 256, 256, 4096, 4096, 8192
  };
  const size_t NEED = (size_t)(1048576 + 524288 + 524288 + 524288 + 1048576) * 4 + 64;
  bool ok = (n_in == 30) && (ws_size >= NEED) && (out_size == BB*NN*HID);
  if (ok) for (int i = 0; i < 30; ++i) ok = ok && (in_sizes[i] == EXP[i]);
  if (!ok) {
    k_zero<<<(BB*NN*HID + 255)/256, 256, 0, stream>>>((unsigned short*)d_out, BB*NN*HID);
    return;
  }

  float* z   = (float*)d_ws;             // [4,1024,4,64]
  float* enc = z   + 1048576;            // [4,1024,128]
  float* qb  = enc + 524288;             // [16,1024,32] (bf16 for gattn, fp32 for fattn)
  float* kb  = qb  + 524288;
  float* vb  = kb  + 524288;             // [16,1024,64] fp32
  int*  flag = (int*)(vb + 1048576);

  k_detect<<<1, 256, 0, stream>>>(d_in[0], flag);

  const void *i_traffic=d_in[0], *i_user=d_in[1], *i_pw=d_in[2], *i_pb=d_in[3],
    *i_mw=d_in[4], *i_mb=d_in[5], *i_ow=d_in[6], *i_ob=d_in[7], *i_f1w=d_in[8],
    *i_f1b=d_in[9], *i_f2w=d_in[10], *i_f2b=d_in[11], *i_l1g=d_in[12],
    *i_l1b=d_in[13], *i_l2g=d_in[14], *i_l2b=d_in[15], *i_gwq=d_in[16],
    *i_gwk=d_in[17], *i_gwv=d_in[18], *i_gf1w=d_in[19], *i_gf1b=d_in[20],
    *i_gf2w=d_in[21], *i_gf2b=d_in[22], *i_gl1g=d_in[23], *i_gl1b=d_in[24],
    *i_gl2g=d_in[25], *i_gl2b=d_in[26], *i_cwq=d_in[27], *i_cwk=d_in[28],
    *i_cwv=d_in[29];

  const int FFG = BB*NN*SEGN/FRW;        // 1024 blocks

  for (int s = 0; s < 2; ++s) {
    const void* x = s ? i_user : i_traffic;
    k_patch<0><<<BB*NN, 256, 0, stream>>>(x, i_pw, (long)s*HID*SEGL, i_pb, (long)s*HID, z, flag);
    k_patch<1><<<BB*NN, 256, 0, stream>>>(x, i_pw, (long)s*HID*SEGL, i_pb, (long)s*HID, z, flag);
    for (int i = 0; i < 2; ++i) {
      long si = s*2 + i;
      k_tattn<0><<<BB*NN, 64, 0, stream>>>(z,
          i_mw, si*3*HID*HID, i_mb, si*3*HID, i_ow, si*HID*HID, i_ob, si*HID,
          i_l1g, si*HID, i_l1b, si*HID, flag);
      k_tattn<1><<<BB*NN, 64, 0, stream>>>(z,
          i_mw, si*3*HID*HID, i_mb, si*3*HID, i_ow, si*HID*HID, i_ob, si*HID,
          i_l1g, si*HID, i_l1b, si*HID, flag);
      k_ffmfma<0><<<FFG, 256, 0, stream>>>(z,
          i_f1w, si*FFD*HID, i_f1b, si*FFD, i_f2w, si*HID*FFD, i_f2b, si*HID,
          i_l2g, si*HID, i_l2b, si*HID, flag);
      k_ffmfma<1><<<FFG, 256, 0, stream>>>(z,
          i_f1w, si*FFD*HID, i_f1b, si*FFD, i_f2w, si*HID*FFD, i_f2b, si*HID,
          i_l2g, si*HID, i_l2b, si*HID, flag);
      k_gqkv<0><<<16*NN, 128, 0, stream>>>(z,
          i_gwq, si*DKK*HID, i_gwk, si*DKK*HID, i_gwv, si*HID*HID,
          (unsigned short*)qb, (unsigned short*)kb, vb, flag);
      k_gqkv<1><<<16*NN, 128, 0, stream>>>(z,
          i_gwq, si*DKK*HID, i_gwk, si*DKK*HID, i_gwv, si*HID*HID,
          (unsigned short*)qb, (unsigned short*)kb, vb, flag);
      k_gattn<<<16*16, 256, 0, stream>>>(z,
          (const unsigned short*)qb, (const unsigned short*)kb, vb,
          i_gl1g, si*HID, i_gl1b, si*HID, flag);
      k_ffmfma<0><<<FFG, 256, 0, stream>>>(z,
          i_gf1w, si*FFD*HID, i_gf1b, si*FFD, i_gf2w, si*HID*FFD, i_gf2b, si*HID,
          i_gl2g, si*HID, i_gl2b, si*HID, flag);
      k_ffmfma<1><<<FFG, 256, 0, stream>>>(z,
          i_gf1w, si*FFD*HID, i_gf1b, si*FFD, i_gf2w, si*HID*FFD, i_gf2b, si*HID,
          i_gl2g, si*HID, i_gl2b, si*HID, flag);
    }
    k_pool<<<BB*NN, 64, 0, stream>>>(z, enc, s);
  }
  k_fqkv<0><<<BB*NN, 128, 0, stream>>>(enc, i_cwq, i_cwk, i_cwv, qb, kb, vb, flag);
  k_fqkv<1><<<BB*NN, 128, 0, stream>>>(enc, i_cwq, i_cwk, i_cwv, qb, kb, vb, flag);
  k_fattn<<<BB*(NN/QB), 256, 0, stream>>>(qb, kb, vb, d_out, flag);
}